// Round 1
// baseline (1415.755 us; speedup 1.0000x reference)
//
#include <hip/hip_runtime.h>

#define LNUM 2
#define BBATCH 2
#define SSEQ 1024
#define DDIM 2048
#define HHEADS 32
#define HDIM 64
#define IDIM 8192
#define MM 2048   // B*S

typedef __attribute__((ext_vector_type(4))) float f32x4;
typedef __attribute__((ext_vector_type(8))) __bf16 bf16x8;
typedef __attribute__((ext_vector_type(4))) unsigned short us4;
typedef __attribute__((ext_vector_type(8))) unsigned short us8;

__device__ __forceinline__ unsigned short f2bf(float f) {
  union { float f; unsigned u; } v; v.f = f;
  unsigned r = v.u + 0x7fffu + ((v.u >> 16) & 1u);
  return (unsigned short)(r >> 16);
}
__device__ __forceinline__ float bf2f(unsigned short b) {
  union { unsigned u; float f; } v; v.u = ((unsigned)b) << 16;
  return v.f;
}

#define GLD16(g, l) __builtin_amdgcn_global_load_lds( \
    (const __attribute__((address_space(1))) void*)(g), \
    (__attribute__((address_space(3))) void*)(l), 16, 0, 0)

// ---------------------------------------------------------------- LayerNorm
// one block per row; fp32 in -> bf16 out (normalized * g + b)
__global__ __launch_bounds__(256) void ln_kernel(
    const float* __restrict__ x, const float* __restrict__ g,
    const float* __restrict__ bta, unsigned short* __restrict__ out)
{
  int tid = threadIdx.x;
  int lane = tid & 63, w = tid >> 6;
  int row = blockIdx.x;
  const float* xr = x + (size_t)row * DDIM;
  const f32x4* xr4 = (const f32x4*)xr;
  f32x4 v[2];
  float s1 = 0.f, s2 = 0.f;
#pragma unroll
  for (int i = 0; i < 2; i++) {
    v[i] = xr4[tid + 256 * i];
#pragma unroll
    for (int j = 0; j < 4; j++) { s1 += v[i][j]; s2 += v[i][j] * v[i][j]; }
  }
#pragma unroll
  for (int m = 1; m < 64; m <<= 1) {
    s1 += __shfl_xor(s1, m);
    s2 += __shfl_xor(s2, m);
  }
  __shared__ float red[8];
  if (lane == 0) { red[w * 2] = s1; red[w * 2 + 1] = s2; }
  __syncthreads();
  s1 = red[0] + red[2] + red[4] + red[6];
  s2 = red[1] + red[3] + red[5] + red[7];
  float mu = s1 / (float)DDIM;
  float var = s2 / (float)DDIM - mu * mu;
  float rstd = rsqrtf(var + 1e-5f);
#pragma unroll
  for (int i = 0; i < 2; i++) {
    int c0 = (tid + 256 * i) * 4;
    us4 o;
#pragma unroll
    for (int j = 0; j < 4; j++)
      o[j] = f2bf((v[i][j] - mu) * rstd * g[c0 + j] + bta[c0 + j]);
    *(us4*)(out + (size_t)row * DDIM + c0) = o;
  }
}

// ------------------------------------------------- weight convert+transpose
// W fp32 [K][N] -> Wt bf16 [N][K]
__global__ __launch_bounds__(256) void cvt_t_kernel(
    const float* __restrict__ W, unsigned short* __restrict__ Wt, int K, int N)
{
  __shared__ float tile[32][33];
  int t = threadIdx.x;
  int k0 = blockIdx.x << 5, n0 = blockIdx.y << 5;
  int r = t >> 3, c4 = (t & 7) << 2;
  f32x4 v = *(const f32x4*)(W + (size_t)(k0 + r) * N + n0 + c4);
  tile[r][c4 + 0] = v[0]; tile[r][c4 + 1] = v[1];
  tile[r][c4 + 2] = v[2]; tile[r][c4 + 3] = v[3];
  __syncthreads();
  us4 o;
#pragma unroll
  for (int j = 0; j < 4; j++) o[j] = f2bf(tile[c4 + j][r]);
  *(us4*)(Wt + (size_t)(n0 + r) * K + k0 + c4) = o;
}

// ----------------------------------------------------------------- GEMM
// C[M,N] = A[M,K] * Bt[N,K]^T (+bias) ; OUTMODE 0: bf16 out, 2: f32 out +=
template<int OUTMODE>
__global__ __launch_bounds__(256) void gemm_kernel(
    const unsigned short* __restrict__ A, const unsigned short* __restrict__ Bt,
    unsigned short* __restrict__ outB, float* __restrict__ outF,
    const float* __restrict__ bias, int M, int N, int K)
{
  __shared__ unsigned short As[128 * 32];
  __shared__ unsigned short Bs[128 * 32];
  int tid = threadIdx.x;
  int lane = tid & 63, w = tid >> 6;
  int m0 = blockIdx.y * 128, n0 = blockIdx.x * 128;
  int wr = w >> 1, wc = w & 1;

  f32x4 z4 = {0.f, 0.f, 0.f, 0.f};
  f32x4 acc[4][4];
#pragma unroll
  for (int i = 0; i < 4; i++)
#pragma unroll
    for (int j = 0; j < 4; j++) acc[i][j] = z4;

  int bofs0 = w * 1024 + lane * 16;
  int bofs1 = (4 + w) * 1024 + lane * 16;
  int r0 = bofs0 >> 6, c0 = (bofs0 & 63) >> 1;
  int r1 = bofs1 >> 6, c1 = (bofs1 & 63) >> 1;
  const unsigned short* a0 = A + (size_t)(m0 + r0) * K + c0;
  const unsigned short* a1 = A + (size_t)(m0 + r1) * K + c1;
  const unsigned short* b0 = Bt + (size_t)(n0 + r0) * K + c0;
  const unsigned short* b1 = Bt + (size_t)(n0 + r1) * K + c1;
  unsigned short* lA0 = As + w * 512;
  unsigned short* lA1 = As + (4 + w) * 512;
  unsigned short* lB0 = Bs + w * 512;
  unsigned short* lB1 = Bs + (4 + w) * 512;

  int arow = wr * 64 + (lane & 15);
  int brow = wc * 64 + (lane & 15);
  int koff = (lane >> 4) * 8;

  for (int kt = 0; kt < K; kt += 32) {
    __syncthreads();
    GLD16(a0 + kt, lA0);
    GLD16(a1 + kt, lA1);
    GLD16(b0 + kt, lB0);
    GLD16(b1 + kt, lB1);
    __syncthreads();
    bf16x8 af[4], bfr[4];
#pragma unroll
    for (int i = 0; i < 4; i++)
      af[i] = *(const bf16x8*)(As + (arow + i * 16) * 32 + koff);
#pragma unroll
    for (int j = 0; j < 4; j++)
      bfr[j] = *(const bf16x8*)(Bs + (brow + j * 16) * 32 + koff);
#pragma unroll
    for (int i = 0; i < 4; i++)
#pragma unroll
      for (int j = 0; j < 4; j++)
        acc[i][j] = __builtin_amdgcn_mfma_f32_16x16x32_bf16(af[i], bfr[j], acc[i][j], 0, 0, 0);
  }

  int grp = lane >> 4, l = lane & 15;
#pragma unroll
  for (int mi = 0; mi < 4; mi++) {
#pragma unroll
    for (int nj = 0; nj < 4; nj++) {
      int col = n0 + wc * 64 + nj * 16 + l;
      float bv = bias ? bias[col] : 0.f;
#pragma unroll
      for (int r = 0; r < 4; r++) {
        int row = m0 + wr * 64 + mi * 16 + grp * 4 + r;
        float v = acc[mi][nj][r] + bv;
        if (OUTMODE == 2) outF[(size_t)row * N + col] += v;
        else outB[(size_t)row * N + col] = f2bf(v);
      }
    }
  }
}

// ----------------------------------------------------------- attention
// qkv bf16 [M][6144] (q|k|v each [h*64+hd]); ctx bf16 [M][2048] = [b,s,h,hd]
__global__ __launch_bounds__(256) void attn_kernel(
    const unsigned short* __restrict__ qkv, const int* __restrict__ amask,
    unsigned short* __restrict__ ctx)
{
  __shared__ unsigned short Qs[128 * 80];
  __shared__ unsigned short Ks[128 * 80];
  __shared__ unsigned short Vt[64 * 144];
  __shared__ unsigned short Ps[128 * 144];

  int tid = threadIdx.x, lane = tid & 63, w = tid >> 6;
  int grp = lane >> 4, l = lane & 15;
  int q0 = blockIdx.x * 128;
  int bh = blockIdx.y;
  int b = bh >> 5, h = bh & 31;
  const size_t rs = 3 * DDIM;  // 6144
  const unsigned short* qbase = qkv + (size_t)(b * SSEQ) * rs + h * HDIM;
  const unsigned short* kbase = qbase + DDIM;
  const unsigned short* vbase = qbase + 2 * DDIM;

  // stage Q tile [128][64] -> Qs stride 80
#pragma unroll
  for (int i = 0; i < 4; i++) {
    int c = tid + 256 * i;
    int r = c >> 3, part = c & 7;
    us8 v = *(const us8*)(qbase + (size_t)(q0 + r) * rs + part * 8);
    *(us8*)(Qs + r * 80 + part * 8) = v;
  }

  float mrun[2][4], lrun[2][4];
  f32x4 z4 = {0.f, 0.f, 0.f, 0.f};
  f32x4 oacc[2][4];
#pragma unroll
  for (int mi = 0; mi < 2; mi++)
#pragma unroll
    for (int r = 0; r < 4; r++) { mrun[mi][r] = -1e30f; lrun[mi][r] = 0.f; }
#pragma unroll
  for (int mi = 0; mi < 2; mi++)
#pragma unroll
    for (int nj = 0; nj < 4; nj++) oacc[mi][nj] = z4;

  for (int kb = 0; kb < 8; kb++) {
    __syncthreads();
    // stage K tile [128][64] -> Ks stride 80
#pragma unroll
    for (int i = 0; i < 4; i++) {
      int c = tid + 256 * i;
      int r = c >> 3, part = c & 7;
      us8 v = *(const us8*)(kbase + (size_t)(kb * 128 + r) * rs + part * 8);
      *(us8*)(Ks + r * 80 + part * 8) = v;
    }
    // stage V transposed: Vt[hd][s], stride 144, XOR swizzle on s8
#pragma unroll
    for (int i = 0; i < 2; i++) {
      int bb = tid + 256 * i;
      int hb = bb & 15, sb = bb >> 4;
      int hd0 = hb * 4, s0 = sb * 4;
      us4 rv[4];
#pragma unroll
      for (int j = 0; j < 4; j++)
        rv[j] = *(const us4*)(vbase + (size_t)(kb * 128 + s0 + j) * rs + hd0);
      int s8 = s0 >> 3, rem = s0 & 7;
#pragma unroll
      for (int j2 = 0; j2 < 4; j2++) {
        int hd = hd0 + j2;
        us4 ov;
        ov[0] = rv[0][j2]; ov[1] = rv[1][j2]; ov[2] = rv[2][j2]; ov[3] = rv[3][j2];
        *(us4*)(Vt + hd * 144 + ((s8 ^ (hd >> 2)) * 8) + rem) = ov;
      }
    }
    __syncthreads();

    // QK^T : per wave rows w*32..+31
    f32x4 sc[2][8];
#pragma unroll
    for (int mi = 0; mi < 2; mi++)
#pragma unroll
      for (int nj = 0; nj < 8; nj++) sc[mi][nj] = z4;
#pragma unroll
    for (int ks = 0; ks < 2; ks++) {
      bf16x8 aq[2];
#pragma unroll
      for (int mi = 0; mi < 2; mi++)
        aq[mi] = *(const bf16x8*)(Qs + (w * 32 + mi * 16 + l) * 80 + ks * 32 + grp * 8);
#pragma unroll
      for (int nj = 0; nj < 8; nj++) {
        bf16x8 bk = *(const bf16x8*)(Ks + (nj * 16 + l) * 80 + ks * 32 + grp * 8);
#pragma unroll
        for (int mi = 0; mi < 2; mi++)
          sc[mi][nj] = __builtin_amdgcn_mfma_f32_16x16x32_bf16(aq[mi], bk, sc[mi][nj], 0, 0, 0);
      }
    }
    // scale + mask
    float mb[8];
#pragma unroll
    for (int nj = 0; nj < 8; nj++) {
      int col = kb * 128 + nj * 16 + l;
      mb[nj] = (1.0f - (float)amask[b * SSEQ + col]) * -10000.0f;
    }
#pragma unroll
    for (int mi = 0; mi < 2; mi++)
#pragma unroll
      for (int nj = 0; nj < 8; nj++)
#pragma unroll
        for (int r = 0; r < 4; r++)
          sc[mi][nj][r] = sc[mi][nj][r] * 0.125f + mb[nj];

    // row max
    float pm[2][4];
#pragma unroll
    for (int mi = 0; mi < 2; mi++)
#pragma unroll
      for (int r = 0; r < 4; r++) {
        float m = sc[mi][0][r];
#pragma unroll
        for (int nj = 1; nj < 8; nj++) m = fmaxf(m, sc[mi][nj][r]);
#pragma unroll
        for (int s = 1; s <= 8; s <<= 1) m = fmaxf(m, __shfl_xor(m, s));
        pm[mi][r] = m;
      }
    // online softmax update
    float corr[2][4];
#pragma unroll
    for (int mi = 0; mi < 2; mi++)
#pragma unroll
      for (int r = 0; r < 4; r++) {
        float nm = fmaxf(mrun[mi][r], pm[mi][r]);
        corr[mi][r] = __expf(mrun[mi][r] - nm);
        mrun[mi][r] = nm;
      }
    float rsum[2][4];
#pragma unroll
    for (int mi = 0; mi < 2; mi++)
#pragma unroll
      for (int r = 0; r < 4; r++) rsum[mi][r] = 0.f;
#pragma unroll
    for (int mi = 0; mi < 2; mi++)
#pragma unroll
      for (int nj = 0; nj < 8; nj++)
#pragma unroll
        for (int r = 0; r < 4; r++) {
          float p = __expf(sc[mi][nj][r] - mrun[mi][r]);
          sc[mi][nj][r] = p;
          rsum[mi][r] += p;
        }
#pragma unroll
    for (int mi = 0; mi < 2; mi++)
#pragma unroll
      for (int r = 0; r < 4; r++) {
        float s = rsum[mi][r];
#pragma unroll
        for (int m = 1; m <= 8; m <<= 1) s += __shfl_xor(s, m);
        lrun[mi][r] = lrun[mi][r] * corr[mi][r] + s;
      }
#pragma unroll
    for (int mi = 0; mi < 2; mi++)
#pragma unroll
      for (int nj = 0; nj < 4; nj++)
#pragma unroll
        for (int r = 0; r < 4; r++) oacc[mi][nj][r] *= corr[mi][r];

    // write P (bf16) to LDS in D-layout positions
#pragma unroll
    for (int mi = 0; mi < 2; mi++)
#pragma unroll
      for (int nj = 0; nj < 8; nj++)
#pragma unroll
        for (int r = 0; r < 4; r++)
          Ps[(w * 32 + mi * 16 + grp * 4 + r) * 144 + nj * 16 + l] = f2bf(sc[mi][nj][r]);
    __syncthreads();

    // PV
#pragma unroll
    for (int ks = 0; ks < 4; ks++) {
      bf16x8 pf[2];
#pragma unroll
      for (int mi = 0; mi < 2; mi++)
        pf[mi] = *(const bf16x8*)(Ps + (w * 32 + mi * 16 + l) * 144 + ks * 32 + grp * 8);
      int s8 = ks * 4 + grp;
#pragma unroll
      for (int nj = 0; nj < 4; nj++) {
        int hd = nj * 16 + l;
        bf16x8 vf = *(const bf16x8*)(Vt + hd * 144 + ((s8 ^ (hd >> 2)) * 8));
#pragma unroll
        for (int mi = 0; mi < 2; mi++)
          oacc[mi][nj] = __builtin_amdgcn_mfma_f32_16x16x32_bf16(pf[mi], vf, oacc[mi][nj], 0, 0, 0);
      }
    }
  }

  // epilogue: ctx[b, q, h*64+hd]
#pragma unroll
  for (int mi = 0; mi < 2; mi++)
#pragma unroll
    for (int nj = 0; nj < 4; nj++)
#pragma unroll
      for (int r = 0; r < 4; r++) {
        int qrow = q0 + w * 32 + mi * 16 + grp * 4 + r;
        int hd = nj * 16 + l;
        float v = oacc[mi][nj][r] / lrun[mi][r];
        ctx[(size_t)(b * SSEQ + qrow) * DDIM + h * HDIM + hd] = f2bf(v);
      }
}

// ----------------------------------------------------------------- swiglu
__global__ __launch_bounds__(256) void swiglu_kernel(
    const unsigned short* __restrict__ gu, unsigned short* __restrict__ a)
{
  size_t idx = ((size_t)blockIdx.x * 256 + threadIdx.x) * 8;
  int r = (int)(idx >> 13);       // / 8192
  int c = (int)(idx & 8191);
  const unsigned short* gp = gu + (size_t)r * (2 * IDIM) + c;
  us8 gv = *(const us8*)gp;
  us8 uv = *(const us8*)(gp + IDIM);
  us8 ov;
#pragma unroll
  for (int j = 0; j < 8; j++) {
    float g = bf2f(gv[j]), u = bf2f(uv[j]);
    ov[j] = f2bf(g / (1.f + __expf(-g)) * u);
  }
  *(us8*)(a + idx) = ov;
}

// ----------------------------------------------------------------- host
extern "C" void kernel_launch(void* const* d_in, const int* in_sizes, int n_in,
                              void* d_out, int out_size, void* d_ws, size_t ws_size,
                              hipStream_t stream) {
  (void)in_sizes; (void)n_in; (void)out_size; (void)ws_size;
  const float* hs    = (const float*)d_in[0];
  const int*   amask = (const int*)d_in[1];
  const float* ln1_g = (const float*)d_in[2];
  const float* ln1_b = (const float*)d_in[3];
  const float* qkv_w = (const float*)d_in[4];
  const float* o_w   = (const float*)d_in[5];
  const float* ln2_g = (const float*)d_in[6];
  const float* ln2_b = (const float*)d_in[7];
  const float* gu_w  = (const float*)d_in[8];
  const float* gu_b  = (const float*)d_in[9];
  const float* down_w = (const float*)d_in[10];
  const float* down_b = (const float*)d_in[11];
  float* out = (float*)d_out;

  char* ws = (char*)d_ws;
  unsigned short* Wt   = (unsigned short*)ws;                    // 67108864 B
  unsigned short* xb   = (unsigned short*)(ws + 67108864);       // 8388608
  unsigned short* qkvb = (unsigned short*)(ws + 75497472);       // 25165824
  unsigned short* ctxb = (unsigned short*)(ws + 100663296);      // 8388608
  unsigned short* gub  = (unsigned short*)(ws + 109051904);      // 67108864
  unsigned short* ab   = qkvb;  // alias: 33554432 over qkvb+ctxb (dead then)

  // h := hidden_states (residual stream lives in d_out, fp32)
  hipMemcpyAsync(out, hs, (size_t)MM * DDIM * sizeof(float),
                 hipMemcpyDeviceToDevice, stream);

  for (int lidx = 0; lidx < LNUM; lidx++) {
    // LN1 -> x (bf16)
    ln_kernel<<<MM, 256, 0, stream>>>(out, ln1_g + lidx * DDIM, ln1_b + lidx * DDIM, xb);
    // qkv = x @ qkv_w
    cvt_t_kernel<<<dim3(DDIM / 32, (3 * DDIM) / 32), 256, 0, stream>>>(
        qkv_w + (size_t)lidx * DDIM * 3 * DDIM, Wt, DDIM, 3 * DDIM);
    gemm_kernel<0><<<dim3((3 * DDIM) / 128, MM / 128), 256, 0, stream>>>(
        xb, Wt, qkvb, nullptr, nullptr, MM, 3 * DDIM, DDIM);
    // attention
    attn_kernel<<<dim3(SSEQ / 128, BBATCH * HHEADS), 256, 0, stream>>>(qkvb, amask, ctxb);
    // h += ctx @ o_w
    cvt_t_kernel<<<dim3(DDIM / 32, DDIM / 32), 256, 0, stream>>>(
        o_w + (size_t)lidx * DDIM * DDIM, Wt, DDIM, DDIM);
    gemm_kernel<2><<<dim3(DDIM / 128, MM / 128), 256, 0, stream>>>(
        ctxb, Wt, nullptr, out, nullptr, MM, DDIM, DDIM);
    // LN2 -> y (bf16, reuse xb)
    ln_kernel<<<MM, 256, 0, stream>>>(out, ln2_g + lidx * DDIM, ln2_b + lidx * DDIM, xb);
    // gu = y @ gu_w + gu_b
    cvt_t_kernel<<<dim3(DDIM / 32, (2 * IDIM) / 32), 256, 0, stream>>>(
        gu_w + (size_t)lidx * DDIM * 2 * IDIM, Wt, DDIM, 2 * IDIM);
    gemm_kernel<0><<<dim3((2 * IDIM) / 128, MM / 128), 256, 0, stream>>>(
        xb, Wt, gub, nullptr, gu_b + (size_t)lidx * 2 * IDIM, MM, 2 * IDIM, DDIM);
    // a = swish(gate) * up
    swiglu_kernel<<<(MM * IDIM / 8) / 256, 256, 0, stream>>>(gub, ab);
    // h += a @ down_w + down_b
    cvt_t_kernel<<<dim3(IDIM / 32, DDIM / 32), 256, 0, stream>>>(
        down_w + (size_t)lidx * IDIM * DDIM, Wt, IDIM, DDIM);
    gemm_kernel<2><<<dim3(DDIM / 128, MM / 128), 256, 0, stream>>>(
        ab, Wt, nullptr, out, down_b + (size_t)lidx * DDIM, MM, DDIM, IDIM);
  }
}

// Round 2
// 1275.263 us; speedup vs baseline: 1.1102x; 1.1102x over previous
//
#include <hip/hip_runtime.h>

#define LNUM 2
#define BBATCH 2
#define SSEQ 1024
#define DDIM 2048
#define HHEADS 32
#define HDIM 64
#define IDIM 8192
#define MM 2048   // B*S

typedef __attribute__((ext_vector_type(4))) float f32x4;
typedef __attribute__((ext_vector_type(8))) __bf16 bf16x8;
typedef __attribute__((ext_vector_type(4))) unsigned short us4;
typedef __attribute__((ext_vector_type(8))) unsigned short us8;

__device__ __forceinline__ unsigned short f2bf(float f) {
  union { float f; unsigned u; } v; v.f = f;
  unsigned r = v.u + 0x7fffu + ((v.u >> 16) & 1u);
  return (unsigned short)(r >> 16);
}
__device__ __forceinline__ float bf2f(unsigned short b) {
  union { unsigned u; float f; } v; v.u = ((unsigned)b) << 16;
  return v.f;
}

#define GLD16(g, l) __builtin_amdgcn_global_load_lds( \
    (const __attribute__((address_space(1))) void*)(g), \
    (__attribute__((address_space(3))) void*)(l), 16, 0, 0)

// ---------------------------------------------------------------- LayerNorm
__global__ __launch_bounds__(256) void ln_kernel(
    const float* __restrict__ x, const float* __restrict__ g,
    const float* __restrict__ bta, unsigned short* __restrict__ out)
{
  int tid = threadIdx.x;
  int lane = tid & 63, w = tid >> 6;
  int row = blockIdx.x;
  const float* xr = x + (size_t)row * DDIM;
  const f32x4* xr4 = (const f32x4*)xr;
  f32x4 v[2];
  float s1 = 0.f, s2 = 0.f;
#pragma unroll
  for (int i = 0; i < 2; i++) {
    v[i] = xr4[tid + 256 * i];
#pragma unroll
    for (int j = 0; j < 4; j++) { s1 += v[i][j]; s2 += v[i][j] * v[i][j]; }
  }
#pragma unroll
  for (int m = 1; m < 64; m <<= 1) {
    s1 += __shfl_xor(s1, m);
    s2 += __shfl_xor(s2, m);
  }
  __shared__ float red[8];
  if (lane == 0) { red[w * 2] = s1; red[w * 2 + 1] = s2; }
  __syncthreads();
  s1 = red[0] + red[2] + red[4] + red[6];
  s2 = red[1] + red[3] + red[5] + red[7];
  float mu = s1 / (float)DDIM;
  float var = s2 / (float)DDIM - mu * mu;
  float rstd = rsqrtf(var + 1e-5f);
#pragma unroll
  for (int i = 0; i < 2; i++) {
    int c0 = (tid + 256 * i) * 4;
    us4 o;
#pragma unroll
    for (int j = 0; j < 4; j++)
      o[j] = f2bf((v[i][j] - mu) * rstd * g[c0 + j] + bta[c0 + j]);
    *(us4*)(out + (size_t)row * DDIM + c0) = o;
  }
}

// ------------------------------------------------- weight convert+transpose
__global__ __launch_bounds__(256) void cvt_t_kernel(
    const float* __restrict__ W, unsigned short* __restrict__ Wt, int K, int N)
{
  __shared__ float tile[32][33];
  int t = threadIdx.x;
  int k0 = blockIdx.x << 5, n0 = blockIdx.y << 5;
  int r = t >> 3, c4 = (t & 7) << 2;
  f32x4 v = *(const f32x4*)(W + (size_t)(k0 + r) * N + n0 + c4);
  tile[r][c4 + 0] = v[0]; tile[r][c4 + 1] = v[1];
  tile[r][c4 + 2] = v[2]; tile[r][c4 + 3] = v[3];
  __syncthreads();
  us4 o;
#pragma unroll
  for (int j = 0; j < 4; j++) o[j] = f2bf(tile[c4 + j][r]);
  *(us4*)(Wt + (size_t)(n0 + r) * K + k0 + c4) = o;
}

// ----------------------------------------------------------------- 128^2 GEMM (m97 structure)
template<int OUTMODE>
__global__ __launch_bounds__(256) void gemm_kernel(
    const unsigned short* __restrict__ A, const unsigned short* __restrict__ Bt,
    unsigned short* __restrict__ outB, float* __restrict__ outF,
    const float* __restrict__ bias, int M, int N, int K)
{
  __shared__ unsigned short As[128 * 32];
  __shared__ unsigned short Bs[128 * 32];
  int tid = threadIdx.x;
  int lane = tid & 63, w = tid >> 6;
  int m0 = blockIdx.y * 128, n0 = blockIdx.x * 128;
  int wr = w >> 1, wc = w & 1;

  f32x4 z4 = {0.f, 0.f, 0.f, 0.f};
  f32x4 acc[4][4];
#pragma unroll
  for (int i = 0; i < 4; i++)
#pragma unroll
    for (int j = 0; j < 4; j++) acc[i][j] = z4;

  int bofs0 = w * 1024 + lane * 16;
  int bofs1 = (4 + w) * 1024 + lane * 16;
  int r0 = bofs0 >> 6, c0 = (bofs0 & 63) >> 1;
  int r1 = bofs1 >> 6, c1 = (bofs1 & 63) >> 1;
  const unsigned short* a0 = A + (size_t)(m0 + r0) * K + c0;
  const unsigned short* a1 = A + (size_t)(m0 + r1) * K + c1;
  const unsigned short* b0 = Bt + (size_t)(n0 + r0) * K + c0;
  const unsigned short* b1 = Bt + (size_t)(n0 + r1) * K + c1;
  unsigned short* lA0 = As + w * 512;
  unsigned short* lA1 = As + (4 + w) * 512;
  unsigned short* lB0 = Bs + w * 512;
  unsigned short* lB1 = Bs + (4 + w) * 512;

  int arow = wr * 64 + (lane & 15);
  int brow = wc * 64 + (lane & 15);
  int koff = (lane >> 4) * 8;

  for (int kt = 0; kt < K; kt += 32) {
    __syncthreads();
    GLD16(a0 + kt, lA0);
    GLD16(a1 + kt, lA1);
    GLD16(b0 + kt, lB0);
    GLD16(b1 + kt, lB1);
    __syncthreads();
    bf16x8 af[4], bfr[4];
#pragma unroll
    for (int i = 0; i < 4; i++)
      af[i] = *(const bf16x8*)(As + (arow + i * 16) * 32 + koff);
#pragma unroll
    for (int j = 0; j < 4; j++)
      bfr[j] = *(const bf16x8*)(Bs + (brow + j * 16) * 32 + koff);
#pragma unroll
    for (int i = 0; i < 4; i++)
#pragma unroll
      for (int j = 0; j < 4; j++)
        acc[i][j] = __builtin_amdgcn_mfma_f32_16x16x32_bf16(af[i], bfr[j], acc[i][j], 0, 0, 0);
  }

  int grp = lane >> 4, l = lane & 15;
#pragma unroll
  for (int mi = 0; mi < 4; mi++) {
#pragma unroll
    for (int nj = 0; nj < 4; nj++) {
      int col = n0 + wc * 64 + nj * 16 + l;
      float bv = bias ? bias[col] : 0.f;
#pragma unroll
      for (int r = 0; r < 4; r++) {
        int row = m0 + wr * 64 + mi * 16 + grp * 4 + r;
        float v = acc[mi][nj][r] + bv;
        if (OUTMODE == 2) outF[(size_t)row * N + col] += v;
        else outB[(size_t)row * N + col] = f2bf(v);
      }
    }
  }
}

// ----------------------------------------------------------------- 256^2 8-phase GEMM
// C[M,N] = A[M,K] * Bt[N,K]^T (+bias), bf16 out. BK=64, 8 waves (2Mx4N),
// per-wave 128x64. T2 XOR-swizzled LDS (both-sides: pre-swizzled global src +
// linear gload_lds dest + swizzled ds_read), T3/T4 counted vmcnt(4), T5 setprio.
#define BAR __builtin_amdgcn_s_barrier()
#define SCHED0 __builtin_amdgcn_sched_barrier(0)
#define LGKM0 { asm volatile("s_waitcnt lgkmcnt(0)" ::: "memory"); SCHED0; }
#define VMC4 { asm volatile("s_waitcnt vmcnt(4)" ::: "memory"); SCHED0; }
#define VMC0 { asm volatile("s_waitcnt vmcnt(0)" ::: "memory"); SCHED0; }

#define STG_A(p,h,t) { \
  GLD16(pA[h][0] + (size_t)(t)*64, smem + ldsA + (p)*32768 + (h)*16384); \
  GLD16(pA[h][1] + (size_t)(t)*64, smem + ldsA + (p)*32768 + (h)*16384 + 8192); }
#define STG_B(p,h,t) { \
  GLD16(pB[h][0] + (size_t)(t)*64, smem + ldsB + (p)*32768 + (h)*16384); \
  GLD16(pB[h][1] + (size_t)(t)*64, smem + ldsB + (p)*32768 + (h)*16384 + 8192); }

#define DSR_A(p, misel, ks) { \
  _Pragma("unroll") \
  for (int mi = 0; mi < 4; mi++) \
    af[mi] = *(const bf16x8*)(smem + (p)*32768 + aRd + ((misel)*64 + mi*16)*128 + ch[ks]); }
#define DSR_B(p, ks) { \
  _Pragma("unroll") \
  for (int nj = 0; nj < 4; nj++) \
    bfr[ks][nj] = *(const bf16x8*)(smem + (p)*32768 + bRd + nj*2048 + ch[ks]); }

#define MFMA16(misel, ks) { \
  _Pragma("unroll") \
  for (int mi = 0; mi < 4; mi++) \
    _Pragma("unroll") \
    for (int nj = 0; nj < 4; nj++) \
      acc[(misel)*4+mi][nj] = __builtin_amdgcn_mfma_f32_16x16x32_bf16( \
          af[mi], bfr[ks][nj], acc[(misel)*4+mi][nj], 0, 0, 0); }

#define TILE(p, t) { \
  /* P1: (mi-lo, ks0) */ \
  DSR_A(p, 0, 0); DSR_B(p, 0); \
  if ((t)+1 < NT) STG_A(1-(p), 0, (t)+1); \
  SCHED0; BAR; LGKM0; \
  __builtin_amdgcn_s_setprio(1); MFMA16(0, 0); __builtin_amdgcn_s_setprio(0); \
  SCHED0; BAR; \
  /* P2: (mi-lo, ks1) */ \
  DSR_A(p, 0, 1); DSR_B(p, 1); \
  if ((t)+1 < NT) STG_A(1-(p), 1, (t)+1); \
  SCHED0; BAR; LGKM0; \
  __builtin_amdgcn_s_setprio(1); MFMA16(0, 1); __builtin_amdgcn_s_setprio(0); \
  SCHED0; BAR; \
  /* P3: (mi-hi, ks0) */ \
  DSR_A(p, 1, 0); \
  if ((t)+2 < NT) STG_B(p, 0, (t)+2); \
  SCHED0; BAR; LGKM0; \
  __builtin_amdgcn_s_setprio(1); MFMA16(1, 0); __builtin_amdgcn_s_setprio(0); \
  SCHED0; BAR; \
  /* P4: (mi-hi, ks1) */ \
  DSR_A(p, 1, 1); \
  if ((t)+2 < NT) STG_B(p, 1, (t)+2); \
  SCHED0; BAR; LGKM0; \
  __builtin_amdgcn_s_setprio(1); MFMA16(1, 1); __builtin_amdgcn_s_setprio(0); \
  if ((t)+2 < NT) { VMC4; } else { VMC0; } \
  SCHED0; BAR; }

template<int OUTMODE>
__global__ __launch_bounds__(512, 2) void gemm256_kernel(
    const unsigned short* __restrict__ A, const unsigned short* __restrict__ Bt,
    unsigned short* __restrict__ outB, float* __restrict__ outF,
    const float* __restrict__ bias, int M, int N, int K)
{
  extern __shared__ char smem[];  // A: [2][256][128B] @0; B: same @65536
  int tid = threadIdx.x;
  int lane = tid & 63, w = tid >> 6;
  int wr = w >> 2, wc = w & 3;
  int l15 = lane & 15, grp = lane >> 4;

  // XCD-aware bijective swizzle (all grids here have nwg % 8 == 0)
  int nwg = gridDim.x * gridDim.y;
  int bid = blockIdx.y * gridDim.x + blockIdx.x;
  int cpx = nwg >> 3;
  int sw = (bid & 7) * cpx + (bid >> 3);
  int bx = sw % gridDim.x, by = sw / gridDim.x;
  int m0 = by * 256, n0 = bx * 256;

  int NT = K >> 6;

  // stage-source addressing (inverse swizzle on global source)
  int srow = lane >> 3;                       // row & 7 of the staged row
  int kcol = ((lane & 7) ^ srow) * 8;         // logical k-chunk * 8 elems
  const unsigned short* pA[2][2];
  const unsigned short* pB[2][2];
#pragma unroll
  for (int h = 0; h < 2; h++)
#pragma unroll
    for (int i = 0; i < 2; i++) {
      pA[h][i] = A  + (size_t)(m0 + h*128 + i*64 + w*8 + srow) * K + kcol;
      pB[h][i] = Bt + (size_t)(n0 + h*128 + i*64 + w*8 + srow) * K + kcol;
    }
  int ldsA = w*1024 + lane*16;
  int ldsB = 65536 + w*1024 + lane*16;

  // ds_read addressing (swizzled)
  int aRd = (wr*128 + l15) * 128;
  int bRd = 65536 + (wc*64 + l15) * 128;
  int ch[2];
  ch[0] = ((0*4 + grp) ^ (l15 & 7)) * 16;
  ch[1] = ((1*4 + grp) ^ (l15 & 7)) * 16;

  f32x4 z4 = {0.f, 0.f, 0.f, 0.f};
  f32x4 acc[8][4];
#pragma unroll
  for (int i = 0; i < 8; i++)
#pragma unroll
    for (int j = 0; j < 4; j++) acc[i][j] = z4;
  bf16x8 af[4];
  bf16x8 bfr[2][4];

  // prologue: tile0 (8 loads) + B halves of tile1 (4 loads); drain to 4
  STG_A(0, 0, 0); STG_A(0, 1, 0); STG_B(0, 0, 0); STG_B(0, 1, 0);
  if (NT > 1) { STG_B(1, 0, 1); STG_B(1, 1, 1); VMC4; } else { VMC0; }
  BAR;

  for (int t = 0; t < NT; t += 2) {   // NT is even for all uses (K=2048/8192)
    TILE(0, t);
    TILE(1, t + 1);
  }

#pragma unroll
  for (int mi = 0; mi < 8; mi++) {
#pragma unroll
    for (int nj = 0; nj < 4; nj++) {
      int col = n0 + wc * 64 + nj * 16 + l15;
      float bv = bias ? bias[col] : 0.f;
#pragma unroll
      for (int r = 0; r < 4; r++) {
        int row = m0 + wr * 128 + mi * 16 + grp * 4 + r;
        float v = acc[mi][nj][r] + bv;
        if (OUTMODE == 2) outF[(size_t)row * N + col] += v;
        else outB[(size_t)row * N + col] = f2bf(v);
      }
    }
  }
}

// ----------------------------------------------------------- attention
__global__ __launch_bounds__(256) void attn_kernel(
    const unsigned short* __restrict__ qkv, const int* __restrict__ amask,
    unsigned short* __restrict__ ctx)
{
  __shared__ unsigned short Qs[128 * 80];
  __shared__ unsigned short Ks[128 * 80];
  __shared__ unsigned short Vt[64 * 144];
  __shared__ unsigned short Ps[128 * 144];

  int tid = threadIdx.x, lane = tid & 63, w = tid >> 6;
  int grp = lane >> 4, l = lane & 15;
  int q0 = blockIdx.x * 128;
  int bh = blockIdx.y;
  int b = bh >> 5, h = bh & 31;
  const size_t rs = 3 * DDIM;
  const unsigned short* qbase = qkv + (size_t)(b * SSEQ) * rs + h * HDIM;
  const unsigned short* kbase = qbase + DDIM;
  const unsigned short* vbase = qbase + 2 * DDIM;

#pragma unroll
  for (int i = 0; i < 4; i++) {
    int c = tid + 256 * i;
    int r = c >> 3, part = c & 7;
    us8 v = *(const us8*)(qbase + (size_t)(q0 + r) * rs + part * 8);
    *(us8*)(Qs + r * 80 + part * 8) = v;
  }

  float mrun[2][4], lrun[2][4];
  f32x4 z4 = {0.f, 0.f, 0.f, 0.f};
  f32x4 oacc[2][4];
#pragma unroll
  for (int mi = 0; mi < 2; mi++)
#pragma unroll
    for (int r = 0; r < 4; r++) { mrun[mi][r] = -1e30f; lrun[mi][r] = 0.f; }
#pragma unroll
  for (int mi = 0; mi < 2; mi++)
#pragma unroll
    for (int nj = 0; nj < 4; nj++) oacc[mi][nj] = z4;

  for (int kb = 0; kb < 8; kb++) {
    __syncthreads();
#pragma unroll
    for (int i = 0; i < 4; i++) {
      int c = tid + 256 * i;
      int r = c >> 3, part = c & 7;
      us8 v = *(const us8*)(kbase + (size_t)(kb * 128 + r) * rs + part * 8);
      *(us8*)(Ks + r * 80 + part * 8) = v;
    }
#pragma unroll
    for (int i = 0; i < 2; i++) {
      int bb = tid + 256 * i;
      int hb = bb & 15, sb = bb >> 4;
      int hd0 = hb * 4, s0 = sb * 4;
      us4 rv[4];
#pragma unroll
      for (int j = 0; j < 4; j++)
        rv[j] = *(const us4*)(vbase + (size_t)(kb * 128 + s0 + j) * rs + hd0);
      int s8 = s0 >> 3, rem = s0 & 7;
#pragma unroll
      for (int j2 = 0; j2 < 4; j2++) {
        int hd = hd0 + j2;
        us4 ov;
        ov[0] = rv[0][j2]; ov[1] = rv[1][j2]; ov[2] = rv[2][j2]; ov[3] = rv[3][j2];
        *(us4*)(Vt + hd * 144 + ((s8 ^ (hd >> 2)) * 8) + rem) = ov;
      }
    }
    __syncthreads();

    f32x4 sc[2][8];
#pragma unroll
    for (int mi = 0; mi < 2; mi++)
#pragma unroll
      for (int nj = 0; nj < 8; nj++) sc[mi][nj] = z4;
#pragma unroll
    for (int ks = 0; ks < 2; ks++) {
      bf16x8 aq[2];
#pragma unroll
      for (int mi = 0; mi < 2; mi++)
        aq[mi] = *(const bf16x8*)(Qs + (w * 32 + mi * 16 + l) * 80 + ks * 32 + grp * 8);
#pragma unroll
      for (int nj = 0; nj < 8; nj++) {
        bf16x8 bk = *(const bf16x8*)(Ks + (nj * 16 + l) * 80 + ks * 32 + grp * 8);
#pragma unroll
        for (int mi = 0; mi < 2; mi++)
          sc[mi][nj] = __builtin_amdgcn_mfma_f32_16x16x32_bf16(aq[mi], bk, sc[mi][nj], 0, 0, 0);
      }
    }
    float mb[8];
#pragma unroll
    for (int nj = 0; nj < 8; nj++) {
      int col = kb * 128 + nj * 16 + l;
      mb[nj] = (1.0f - (float)amask[b * SSEQ + col]) * -10000.0f;
    }
#pragma unroll
    for (int mi = 0; mi < 2; mi++)
#pragma unroll
      for (int nj = 0; nj < 8; nj++)
#pragma unroll
        for (int r = 0; r < 4; r++)
          sc[mi][nj][r] = sc[mi][nj][r] * 0.125f + mb[nj];

    float pm[2][4];
#pragma unroll
    for (int mi = 0; mi < 2; mi++)
#pragma unroll
      for (int r = 0; r < 4; r++) {
        float m = sc[mi][0][r];
#pragma unroll
        for (int nj = 1; nj < 8; nj++) m = fmaxf(m, sc[mi][nj][r]);
#pragma unroll
        for (int s = 1; s <= 8; s <<= 1) m = fmaxf(m, __shfl_xor(m, s));
        pm[mi][r] = m;
      }
    float corr[2][4];
#pragma unroll
    for (int mi = 0; mi < 2; mi++)
#pragma unroll
      for (int r = 0; r < 4; r++) {
        float nm = fmaxf(mrun[mi][r], pm[mi][r]);
        corr[mi][r] = __expf(mrun[mi][r] - nm);
        mrun[mi][r] = nm;
      }
    float rsum[2][4];
#pragma unroll
    for (int mi = 0; mi < 2; mi++)
#pragma unroll
      for (int r = 0; r < 4; r++) rsum[mi][r] = 0.f;
#pragma unroll
    for (int mi = 0; mi < 2; mi++)
#pragma unroll
      for (int nj = 0; nj < 8; nj++)
#pragma unroll
        for (int r = 0; r < 4; r++) {
          float p = __expf(sc[mi][nj][r] - mrun[mi][r]);
          sc[mi][nj][r] = p;
          rsum[mi][r] += p;
        }
#pragma unroll
    for (int mi = 0; mi < 2; mi++)
#pragma unroll
      for (int r = 0; r < 4; r++) {
        float s = rsum[mi][r];
#pragma unroll
        for (int m = 1; m <= 8; m <<= 1) s += __shfl_xor(s, m);
        lrun[mi][r] = lrun[mi][r] * corr[mi][r] + s;
      }
#pragma unroll
    for (int mi = 0; mi < 2; mi++)
#pragma unroll
      for (int nj = 0; nj < 4; nj++)
#pragma unroll
        for (int r = 0; r < 4; r++) oacc[mi][nj][r] *= corr[mi][r];

#pragma unroll
    for (int mi = 0; mi < 2; mi++)
#pragma unroll
      for (int nj = 0; nj < 8; nj++)
#pragma unroll
        for (int r = 0; r < 4; r++)
          Ps[(w * 32 + mi * 16 + grp * 4 + r) * 144 + nj * 16 + l] = f2bf(sc[mi][nj][r]);
    __syncthreads();

#pragma unroll
    for (int ks = 0; ks < 4; ks++) {
      bf16x8 pf[2];
#pragma unroll
      for (int mi = 0; mi < 2; mi++)
        pf[mi] = *(const bf16x8*)(Ps + (w * 32 + mi * 16 + l) * 144 + ks * 32 + grp * 8);
      int s8 = ks * 4 + grp;
#pragma unroll
      for (int nj = 0; nj < 4; nj++) {
        int hd = nj * 16 + l;
        bf16x8 vf = *(const bf16x8*)(Vt + hd * 144 + ((s8 ^ (hd >> 2)) * 8));
#pragma unroll
        for (int mi = 0; mi < 2; mi++)
          oacc[mi][nj] = __builtin_amdgcn_mfma_f32_16x16x32_bf16(pf[mi], vf, oacc[mi][nj], 0, 0, 0);
      }
    }
  }

#pragma unroll
  for (int mi = 0; mi < 2; mi++)
#pragma unroll
    for (int nj = 0; nj < 4; nj++)
#pragma unroll
      for (int r = 0; r < 4; r++) {
        int qrow = q0 + w * 32 + mi * 16 + grp * 4 + r;
        int hd = nj * 16 + l;
        float v = oacc[mi][nj][r] / lrun[mi][r];
        ctx[(size_t)(b * SSEQ + qrow) * DDIM + h * HDIM + hd] = f2bf(v);
      }
}

// ----------------------------------------------------------------- swiglu
__global__ __launch_bounds__(256) void swiglu_kernel(
    const unsigned short* __restrict__ gu, unsigned short* __restrict__ a)
{
  size_t idx = ((size_t)blockIdx.x * 256 + threadIdx.x) * 8;
  int r = (int)(idx >> 13);
  int c = (int)(idx & 8191);
  const unsigned short* gp = gu + (size_t)r * (2 * IDIM) + c;
  us8 gv = *(const us8*)gp;
  us8 uv = *(const us8*)(gp + IDIM);
  us8 ov;
#pragma unroll
  for (int j = 0; j < 8; j++) {
    float g = bf2f(gv[j]), u = bf2f(uv[j]);
    ov[j] = f2bf(g / (1.f + __expf(-g)) * u);
  }
  *(us8*)(a + idx) = ov;
}

// ----------------------------------------------------------------- host
extern "C" void kernel_launch(void* const* d_in, const int* in_sizes, int n_in,
                              void* d_out, int out_size, void* d_ws, size_t ws_size,
                              hipStream_t stream) {
  (void)in_sizes; (void)n_in; (void)out_size; (void)ws_size;
  const float* hs    = (const float*)d_in[0];
  const int*   amask = (const int*)d_in[1];
  const float* ln1_g = (const float*)d_in[2];
  const float* ln1_b = (const float*)d_in[3];
  const float* qkv_w = (const float*)d_in[4];
  const float* o_w   = (const float*)d_in[5];
  const float* ln2_g = (const float*)d_in[6];
  const float* ln2_b = (const float*)d_in[7];
  const float* gu_w  = (const float*)d_in[8];
  const float* gu_b  = (const float*)d_in[9];
  const float* down_w = (const float*)d_in[10];
  const float* down_b = (const float*)d_in[11];
  float* out = (float*)d_out;

  char* ws = (char*)d_ws;
  unsigned short* Wt   = (unsigned short*)ws;                    // 67108864 B
  unsigned short* xb   = (unsigned short*)(ws + 67108864);       // 8388608
  unsigned short* qkvb = (unsigned short*)(ws + 75497472);       // 25165824
  unsigned short* ctxb = (unsigned short*)(ws + 100663296);      // 8388608
  unsigned short* gub  = (unsigned short*)(ws + 109051904);      // 67108864
  unsigned short* ab   = qkvb;

  // enable 128 KiB dynamic LDS for the 8-phase kernel (deterministic; falls
  // back to the 128^2 kernel if refused)
  hipError_t eAttr = hipFuncSetAttribute(
      reinterpret_cast<const void*>(&gemm256_kernel<0>),
      hipFuncAttributeMaxDynamicSharedMemorySize, 131072);
  bool use256 = (eAttr == hipSuccess);

  hipMemcpyAsync(out, hs, (size_t)MM * DDIM * sizeof(float),
                 hipMemcpyDeviceToDevice, stream);

  for (int lidx = 0; lidx < LNUM; lidx++) {
    ln_kernel<<<MM, 256, 0, stream>>>(out, ln1_g + lidx * DDIM, ln1_b + lidx * DDIM, xb);
    cvt_t_kernel<<<dim3(DDIM / 32, (3 * DDIM) / 32), 256, 0, stream>>>(
        qkv_w + (size_t)lidx * DDIM * 3 * DDIM, Wt, DDIM, 3 * DDIM);
    if (use256)
      gemm256_kernel<0><<<dim3((3 * DDIM) / 256, MM / 256), 512, 131072, stream>>>(
          xb, Wt, qkvb, nullptr, nullptr, MM, 3 * DDIM, DDIM);
    else
      gemm_kernel<0><<<dim3((3 * DDIM) / 128, MM / 128), 256, 0, stream>>>(
          xb, Wt, qkvb, nullptr, nullptr, MM, 3 * DDIM, DDIM);
    attn_kernel<<<dim3(SSEQ / 128, BBATCH * HHEADS), 256, 0, stream>>>(qkvb, amask, ctxb);
    cvt_t_kernel<<<dim3(DDIM / 32, DDIM / 32), 256, 0, stream>>>(
        o_w + (size_t)lidx * DDIM * DDIM, Wt, DDIM, DDIM);
    gemm_kernel<2><<<dim3(DDIM / 128, MM / 128), 256, 0, stream>>>(
        ctxb, Wt, nullptr, out, nullptr, MM, DDIM, DDIM);
    ln_kernel<<<MM, 256, 0, stream>>>(out, ln2_g + lidx * DDIM, ln2_b + lidx * DDIM, xb);
    cvt_t_kernel<<<dim3(DDIM / 32, (2 * IDIM) / 32), 256, 0, stream>>>(
        gu_w + (size_t)lidx * DDIM * 2 * IDIM, Wt, DDIM, 2 * IDIM);
    if (use256)
      gemm256_kernel<0><<<dim3((2 * IDIM) / 256, MM / 256), 512, 131072, stream>>>(
          xb, Wt, gub, nullptr, gu_b + (size_t)lidx * 2 * IDIM, MM, 2 * IDIM, DDIM);
    else
      gemm_kernel<0><<<dim3((2 * IDIM) / 128, MM / 128), 256, 0, stream>>>(
          xb, Wt, gub, nullptr, gu_b + (size_t)lidx * 2 * IDIM, MM, 2 * IDIM, DDIM);
    swiglu_kernel<<<(MM * IDIM / 8) / 256, 256, 0, stream>>>(gub, ab);
    cvt_t_kernel<<<dim3(IDIM / 32, DDIM / 32), 256, 0, stream>>>(
        down_w + (size_t)lidx * IDIM * DDIM, Wt, IDIM, DDIM);
    gemm_kernel<2><<<dim3(DDIM / 128, MM / 128), 256, 0, stream>>>(
        ab, Wt, nullptr, out, down_b + (size_t)lidx * DDIM, MM, DDIM, IDIM);
  }
}

// Round 3
// 1033.903 us; speedup vs baseline: 1.3693x; 1.2334x over previous
//
#include <hip/hip_runtime.h>

#define LNUM 2
#define BBATCH 2
#define SSEQ 1024
#define DDIM 2048
#define HHEADS 32
#define HDIM 64
#define IDIM 8192
#define MM 2048   // B*S

typedef __attribute__((ext_vector_type(4))) float f32x4;
typedef __attribute__((ext_vector_type(8))) __bf16 bf16x8;
typedef __attribute__((ext_vector_type(4))) unsigned short us4;
typedef __attribute__((ext_vector_type(8))) unsigned short us8;

__device__ __forceinline__ unsigned short f2bf(float f) {
  union { float f; unsigned u; } v; v.f = f;
  unsigned r = v.u + 0x7fffu + ((v.u >> 16) & 1u);
  return (unsigned short)(r >> 16);
}
__device__ __forceinline__ float bf2f(unsigned short b) {
  union { unsigned u; float f; } v; v.u = ((unsigned)b) << 16;
  return v.f;
}

#define GLD16(g, l) __builtin_amdgcn_global_load_lds( \
    (const __attribute__((address_space(1))) void*)(g), \
    (__attribute__((address_space(3))) void*)(l), 16, 0, 0)

// ---------------------------------------------------------------- LayerNorm
// REDSPLIT=0: plain LN. REDSPLIT=4: first do x_row += sum of 4 fp32 partial
// rows (+bias), write x back, then LN. fp32 in -> bf16 out.
template<int REDSPLIT>
__global__ __launch_bounds__(256) void ln_kernel(
    float* __restrict__ x, const float* __restrict__ part,
    const float* __restrict__ rbias,
    const float* __restrict__ g, const float* __restrict__ bta,
    unsigned short* __restrict__ out)
{
  int tid = threadIdx.x;
  int lane = tid & 63, w = tid >> 6;
  int row = blockIdx.x;
  float* xr = x + (size_t)row * DDIM;
  f32x4* xr4 = (f32x4*)xr;
  f32x4 v[2];
  float s1 = 0.f, s2 = 0.f;
#pragma unroll
  for (int i = 0; i < 2; i++) {
    int idx4 = tid + 256 * i;
    v[i] = xr4[idx4];
    if (REDSPLIT > 0) {
#pragma unroll
      for (int s = 0; s < REDSPLIT; s++) {
        f32x4 p = *(const f32x4*)(part + (size_t)s * MM * DDIM + (size_t)row * DDIM + idx4 * 4);
        v[i] += p;
      }
      if (rbias) {
        f32x4 bv = *(const f32x4*)(rbias + idx4 * 4);
        v[i] += bv;
      }
      xr4[idx4] = v[i];
    }
#pragma unroll
    for (int j = 0; j < 4; j++) { s1 += v[i][j]; s2 += v[i][j] * v[i][j]; }
  }
#pragma unroll
  for (int m = 1; m < 64; m <<= 1) {
    s1 += __shfl_xor(s1, m);
    s2 += __shfl_xor(s2, m);
  }
  __shared__ float red[8];
  if (lane == 0) { red[w * 2] = s1; red[w * 2 + 1] = s2; }
  __syncthreads();
  s1 = red[0] + red[2] + red[4] + red[6];
  s2 = red[1] + red[3] + red[5] + red[7];
  float mu = s1 / (float)DDIM;
  float var = s2 / (float)DDIM - mu * mu;
  float rstd = rsqrtf(var + 1e-5f);
#pragma unroll
  for (int i = 0; i < 2; i++) {
    int c0 = (tid + 256 * i) * 4;
    us4 o;
#pragma unroll
    for (int j = 0; j < 4; j++)
      o[j] = f2bf((v[i][j] - mu) * rstd * g[c0 + j] + bta[c0 + j]);
    *(us4*)(out + (size_t)row * DDIM + c0) = o;
  }
}

// --------------------------------------------------- final split-K reduce
__global__ __launch_bounds__(256) void red_kernel(
    float* __restrict__ out, const float* __restrict__ part,
    const float* __restrict__ bias)
{
  size_t i = (size_t)blockIdx.x * 256 + threadIdx.x;   // f32x4 index
  f32x4 o = ((f32x4*)out)[i];
#pragma unroll
  for (int s = 0; s < 4; s++)
    o += *(const f32x4*)(part + (size_t)s * MM * DDIM + i * 4);
  int col4 = (int)((i * 4) & (DDIM - 1));
  f32x4 bv = *(const f32x4*)(bias + col4);
  o += bv;
  ((f32x4*)out)[i] = o;
}

// ------------------------------------------------- weight convert+transpose
__global__ __launch_bounds__(256) void cvt_t_kernel(
    const float* __restrict__ W, unsigned short* __restrict__ Wt, int K, int N)
{
  __shared__ float tile[32][33];
  int t = threadIdx.x;
  int k0 = blockIdx.x << 5, n0 = blockIdx.y << 5;
  int r = t >> 3, c4 = (t & 7) << 2;
  f32x4 v = *(const f32x4*)(W + (size_t)(k0 + r) * N + n0 + c4);
  tile[r][c4 + 0] = v[0]; tile[r][c4 + 1] = v[1];
  tile[r][c4 + 2] = v[2]; tile[r][c4 + 3] = v[3];
  __syncthreads();
  us4 o;
#pragma unroll
  for (int j = 0; j < 4; j++) o[j] = f2bf(tile[c4 + j][r]);
  *(us4*)(Wt + (size_t)(n0 + r) * K + k0 + c4) = o;
}

// ----------------------------------------------------------------- 128^2 GEMM (fallback)
template<int OUTMODE>
__global__ __launch_bounds__(256) void gemm_kernel(
    const unsigned short* __restrict__ A, const unsigned short* __restrict__ Bt,
    unsigned short* __restrict__ outB, float* __restrict__ outF,
    const float* __restrict__ bias, int M, int N, int K)
{
  __shared__ unsigned short As[128 * 32];
  __shared__ unsigned short Bs[128 * 32];
  int tid = threadIdx.x;
  int lane = tid & 63, w = tid >> 6;
  int m0 = blockIdx.y * 128, n0 = blockIdx.x * 128;
  int wr = w >> 1, wc = w & 1;

  f32x4 z4 = {0.f, 0.f, 0.f, 0.f};
  f32x4 acc[4][4];
#pragma unroll
  for (int i = 0; i < 4; i++)
#pragma unroll
    for (int j = 0; j < 4; j++) acc[i][j] = z4;

  int bofs0 = w * 1024 + lane * 16;
  int bofs1 = (4 + w) * 1024 + lane * 16;
  int r0 = bofs0 >> 6, c0 = (bofs0 & 63) >> 1;
  int r1 = bofs1 >> 6, c1 = (bofs1 & 63) >> 1;
  const unsigned short* a0 = A + (size_t)(m0 + r0) * K + c0;
  const unsigned short* a1 = A + (size_t)(m0 + r1) * K + c1;
  const unsigned short* b0 = Bt + (size_t)(n0 + r0) * K + c0;
  const unsigned short* b1 = Bt + (size_t)(n0 + r1) * K + c1;
  unsigned short* lA0 = As + w * 512;
  unsigned short* lA1 = As + (4 + w) * 512;
  unsigned short* lB0 = Bs + w * 512;
  unsigned short* lB1 = Bs + (4 + w) * 512;

  int arow = wr * 64 + (lane & 15);
  int brow = wc * 64 + (lane & 15);
  int koff = (lane >> 4) * 8;

  for (int kt = 0; kt < K; kt += 32) {
    __syncthreads();
    GLD16(a0 + kt, lA0);
    GLD16(a1 + kt, lA1);
    GLD16(b0 + kt, lB0);
    GLD16(b1 + kt, lB1);
    __syncthreads();
    bf16x8 af[4], bfr[4];
#pragma unroll
    for (int i = 0; i < 4; i++)
      af[i] = *(const bf16x8*)(As + (arow + i * 16) * 32 + koff);
#pragma unroll
    for (int j = 0; j < 4; j++)
      bfr[j] = *(const bf16x8*)(Bs + (brow + j * 16) * 32 + koff);
#pragma unroll
    for (int i = 0; i < 4; i++)
#pragma unroll
      for (int j = 0; j < 4; j++)
        acc[i][j] = __builtin_amdgcn_mfma_f32_16x16x32_bf16(af[i], bfr[j], acc[i][j], 0, 0, 0);
  }

  int grp = lane >> 4, l = lane & 15;
#pragma unroll
  for (int mi = 0; mi < 4; mi++) {
#pragma unroll
    for (int nj = 0; nj < 4; nj++) {
      int col = n0 + wc * 64 + nj * 16 + l;
      float bv = bias ? bias[col] : 0.f;
#pragma unroll
      for (int r = 0; r < 4; r++) {
        int row = m0 + wr * 64 + mi * 16 + grp * 4 + r;
        float v = acc[mi][nj][r] + bv;
        if (OUTMODE == 2) outF[(size_t)row * N + col] += v;
        else outB[(size_t)row * N + col] = f2bf(v);
      }
    }
  }
}

// ----------------------------------------------------------------- 256^2 8-phase GEMM
// C[M,N] = A[M,K] * Bt[N,K]^T. OUTMODE 0: bf16 out (+bias).
// OUTMODE 1: fp32 partial out at outF + z*M*N (split-K; A/Bt offset z*Kc).
// BK=64, 8 waves (2Mx4N). T2 XOR swizzle both-sides, T3/T4 counted vmcnt, T5 setprio.
#define BAR __builtin_amdgcn_s_barrier()
#define SCHED0 __builtin_amdgcn_sched_barrier(0)
#define LGKM0 { asm volatile("s_waitcnt lgkmcnt(0)" ::: "memory"); SCHED0; }
#define VMC4 { asm volatile("s_waitcnt vmcnt(4)" ::: "memory"); SCHED0; }
#define VMC0 { asm volatile("s_waitcnt vmcnt(0)" ::: "memory"); SCHED0; }

#define STG_A(p,h,t) { \
  GLD16(pA[h][0] + (size_t)(t)*64, smem + ldsA + (p)*32768 + (h)*16384); \
  GLD16(pA[h][1] + (size_t)(t)*64, smem + ldsA + (p)*32768 + (h)*16384 + 8192); }
#define STG_B(p,h,t) { \
  GLD16(pB[h][0] + (size_t)(t)*64, smem + ldsB + (p)*32768 + (h)*16384); \
  GLD16(pB[h][1] + (size_t)(t)*64, smem + ldsB + (p)*32768 + (h)*16384 + 8192); }

#define DSR_A(p, misel, ks) { \
  _Pragma("unroll") \
  for (int mi = 0; mi < 4; mi++) \
    af[mi] = *(const bf16x8*)(smem + (p)*32768 + aRd + ((misel)*64 + mi*16)*128 + ch[ks]); }
#define DSR_B(p, ks) { \
  _Pragma("unroll") \
  for (int nj = 0; nj < 4; nj++) \
    bfr[ks][nj] = *(const bf16x8*)(smem + (p)*32768 + bRd + nj*2048 + ch[ks]); }

#define MFMA16(misel, ks) { \
  _Pragma("unroll") \
  for (int mi = 0; mi < 4; mi++) \
    _Pragma("unroll") \
    for (int nj = 0; nj < 4; nj++) \
      acc[(misel)*4+mi][nj] = __builtin_amdgcn_mfma_f32_16x16x32_bf16( \
          af[mi], bfr[ks][nj], acc[(misel)*4+mi][nj], 0, 0, 0); }

#define TILE(p, t) { \
  DSR_A(p, 0, 0); DSR_B(p, 0); \
  if ((t)+1 < NT) STG_A(1-(p), 0, (t)+1); \
  SCHED0; BAR; LGKM0; \
  __builtin_amdgcn_s_setprio(1); MFMA16(0, 0); __builtin_amdgcn_s_setprio(0); \
  SCHED0; BAR; \
  DSR_A(p, 0, 1); DSR_B(p, 1); \
  if ((t)+1 < NT) STG_A(1-(p), 1, (t)+1); \
  SCHED0; BAR; LGKM0; \
  __builtin_amdgcn_s_setprio(1); MFMA16(0, 1); __builtin_amdgcn_s_setprio(0); \
  SCHED0; BAR; \
  DSR_A(p, 1, 0); \
  if ((t)+2 < NT) STG_B(p, 0, (t)+2); \
  SCHED0; BAR; LGKM0; \
  __builtin_amdgcn_s_setprio(1); MFMA16(1, 0); __builtin_amdgcn_s_setprio(0); \
  SCHED0; BAR; \
  DSR_A(p, 1, 1); \
  if ((t)+2 < NT) STG_B(p, 1, (t)+2); \
  SCHED0; BAR; LGKM0; \
  __builtin_amdgcn_s_setprio(1); MFMA16(1, 1); __builtin_amdgcn_s_setprio(0); \
  if ((t)+2 < NT) { VMC4; } else { VMC0; } \
  SCHED0; BAR; }

template<int OUTMODE>
__global__ __launch_bounds__(512, 2) void gemm256_kernel(
    const unsigned short* __restrict__ A, const unsigned short* __restrict__ Bt,
    unsigned short* __restrict__ outB, float* __restrict__ outF,
    const float* __restrict__ bias, int M, int N, int Kstride, int Kc)
{
  extern __shared__ char smem[];  // A: [2][256][128B] @0; B: same @65536
  int tid = threadIdx.x;
  int lane = tid & 63, w = tid >> 6;
  int wr = w >> 2, wc = w & 3;
  int l15 = lane & 15, grp = lane >> 4;

  int nwg = gridDim.x * gridDim.y;
  int bid = blockIdx.y * gridDim.x + blockIdx.x;
  int cpx = nwg >> 3;
  int sw = (bid & 7) * cpx + (bid >> 3);
  int bx = sw % gridDim.x, by = sw / gridDim.x;
  int m0 = by * 256, n0 = bx * 256;

  int NT = Kc >> 6;
  const unsigned short* Az = A  + (size_t)blockIdx.z * Kc;
  const unsigned short* Bz = Bt + (size_t)blockIdx.z * Kc;

  int srow = lane >> 3;
  int kcol = ((lane & 7) ^ srow) * 8;
  const unsigned short* pA[2][2];
  const unsigned short* pB[2][2];
#pragma unroll
  for (int h = 0; h < 2; h++)
#pragma unroll
    for (int i = 0; i < 2; i++) {
      pA[h][i] = Az + (size_t)(m0 + h*128 + i*64 + w*8 + srow) * Kstride + kcol;
      pB[h][i] = Bz + (size_t)(n0 + h*128 + i*64 + w*8 + srow) * Kstride + kcol;
    }
  int ldsA = w*1024 + lane*16;
  int ldsB = 65536 + w*1024 + lane*16;

  int aRd = (wr*128 + l15) * 128;
  int bRd = 65536 + (wc*64 + l15) * 128;
  int ch[2];
  ch[0] = ((0*4 + grp) ^ (l15 & 7)) * 16;
  ch[1] = ((1*4 + grp) ^ (l15 & 7)) * 16;

  f32x4 z4 = {0.f, 0.f, 0.f, 0.f};
  f32x4 acc[8][4];
#pragma unroll
  for (int i = 0; i < 8; i++)
#pragma unroll
    for (int j = 0; j < 4; j++) acc[i][j] = z4;
  bf16x8 af[4];
  bf16x8 bfr[2][4];

  STG_A(0, 0, 0); STG_A(0, 1, 0); STG_B(0, 0, 0); STG_B(0, 1, 0);
  if (NT > 1) { STG_B(1, 0, 1); STG_B(1, 1, 1); VMC4; } else { VMC0; }
  BAR;

  for (int t = 0; t < NT; t += 2) {   // NT even for all uses (8/24/32)
    TILE(0, t);
    TILE(1, t + 1);
  }

#pragma unroll
  for (int mi = 0; mi < 8; mi++) {
#pragma unroll
    for (int nj = 0; nj < 4; nj++) {
      int col = n0 + wc * 64 + nj * 16 + l15;
      float bv = (OUTMODE == 0 && bias) ? bias[col] : 0.f;
#pragma unroll
      for (int r = 0; r < 4; r++) {
        int row = m0 + wr * 128 + mi * 16 + grp * 4 + r;
        float v = acc[mi][nj][r] + bv;
        if (OUTMODE == 1)
          outF[(size_t)blockIdx.z * M * N + (size_t)row * N + col] = v;
        else
          outB[(size_t)row * N + col] = f2bf(v);
      }
    }
  }
}

// ----------------------------------------------------------- attention
__global__ __launch_bounds__(256) void attn_kernel(
    const unsigned short* __restrict__ qkv, const int* __restrict__ amask,
    unsigned short* __restrict__ ctx)
{
  __shared__ unsigned short Qs[128 * 80];
  __shared__ unsigned short Ks[128 * 80];
  __shared__ unsigned short Vt[64 * 144];
  __shared__ unsigned short Ps[128 * 144];

  int tid = threadIdx.x, lane = tid & 63, w = tid >> 6;
  int grp = lane >> 4, l = lane & 15;
  int q0 = blockIdx.x * 128;
  int bh = blockIdx.y;
  int b = bh >> 5, h = bh & 31;
  const size_t rs = 3 * DDIM;
  const unsigned short* qbase = qkv + (size_t)(b * SSEQ) * rs + h * HDIM;
  const unsigned short* kbase = qbase + DDIM;
  const unsigned short* vbase = qbase + 2 * DDIM;

#pragma unroll
  for (int i = 0; i < 4; i++) {
    int c = tid + 256 * i;
    int r = c >> 3, part = c & 7;
    us8 v = *(const us8*)(qbase + (size_t)(q0 + r) * rs + part * 8);
    *(us8*)(Qs + r * 80 + part * 8) = v;
  }

  float mrun[2][4], lrun[2][4];
  f32x4 z4 = {0.f, 0.f, 0.f, 0.f};
  f32x4 oacc[2][4];
#pragma unroll
  for (int mi = 0; mi < 2; mi++)
#pragma unroll
    for (int r = 0; r < 4; r++) { mrun[mi][r] = -1e30f; lrun[mi][r] = 0.f; }
#pragma unroll
  for (int mi = 0; mi < 2; mi++)
#pragma unroll
    for (int nj = 0; nj < 4; nj++) oacc[mi][nj] = z4;

  for (int kb = 0; kb < 8; kb++) {
    __syncthreads();
#pragma unroll
    for (int i = 0; i < 4; i++) {
      int c = tid + 256 * i;
      int r = c >> 3, part = c & 7;
      us8 v = *(const us8*)(kbase + (size_t)(kb * 128 + r) * rs + part * 8);
      *(us8*)(Ks + r * 80 + part * 8) = v;
    }
#pragma unroll
    for (int i = 0; i < 2; i++) {
      int bb = tid + 256 * i;
      int hb = bb & 15, sb = bb >> 4;
      int hd0 = hb * 4, s0 = sb * 4;
      us4 rv[4];
#pragma unroll
      for (int j = 0; j < 4; j++)
        rv[j] = *(const us4*)(vbase + (size_t)(kb * 128 + s0 + j) * rs + hd0);
      int s8 = s0 >> 3, rem = s0 & 7;
#pragma unroll
      for (int j2 = 0; j2 < 4; j2++) {
        int hd = hd0 + j2;
        us4 ov;
        ov[0] = rv[0][j2]; ov[1] = rv[1][j2]; ov[2] = rv[2][j2]; ov[3] = rv[3][j2];
        *(us4*)(Vt + hd * 144 + ((s8 ^ (hd >> 2)) * 8) + rem) = ov;
      }
    }
    __syncthreads();

    f32x4 sc[2][8];
#pragma unroll
    for (int mi = 0; mi < 2; mi++)
#pragma unroll
      for (int nj = 0; nj < 8; nj++) sc[mi][nj] = z4;
#pragma unroll
    for (int ks = 0; ks < 2; ks++) {
      bf16x8 aq[2];
#pragma unroll
      for (int mi = 0; mi < 2; mi++)
        aq[mi] = *(const bf16x8*)(Qs + (w * 32 + mi * 16 + l) * 80 + ks * 32 + grp * 8);
#pragma unroll
      for (int nj = 0; nj < 8; nj++) {
        bf16x8 bk = *(const bf16x8*)(Ks + (nj * 16 + l) * 80 + ks * 32 + grp * 8);
#pragma unroll
        for (int mi = 0; mi < 2; mi++)
          sc[mi][nj] = __builtin_amdgcn_mfma_f32_16x16x32_bf16(aq[mi], bk, sc[mi][nj], 0, 0, 0);
      }
    }
    float mb[8];
#pragma unroll
    for (int nj = 0; nj < 8; nj++) {
      int col = kb * 128 + nj * 16 + l;
      mb[nj] = (1.0f - (float)amask[b * SSEQ + col]) * -10000.0f;
    }
#pragma unroll
    for (int mi = 0; mi < 2; mi++)
#pragma unroll
      for (int nj = 0; nj < 8; nj++)
#pragma unroll
        for (int r = 0; r < 4; r++)
          sc[mi][nj][r] = sc[mi][nj][r] * 0.125f + mb[nj];

    float pm[2][4];
#pragma unroll
    for (int mi = 0; mi < 2; mi++)
#pragma unroll
      for (int r = 0; r < 4; r++) {
        float m = sc[mi][0][r];
#pragma unroll
        for (int nj = 1; nj < 8; nj++) m = fmaxf(m, sc[mi][nj][r]);
#pragma unroll
        for (int s = 1; s <= 8; s <<= 1) m = fmaxf(m, __shfl_xor(m, s));
        pm[mi][r] = m;
      }
    float corr[2][4];
#pragma unroll
    for (int mi = 0; mi < 2; mi++)
#pragma unroll
      for (int r = 0; r < 4; r++) {
        float nm = fmaxf(mrun[mi][r], pm[mi][r]);
        corr[mi][r] = __expf(mrun[mi][r] - nm);
        mrun[mi][r] = nm;
      }
    float rsum[2][4];
#pragma unroll
    for (int mi = 0; mi < 2; mi++)
#pragma unroll
      for (int r = 0; r < 4; r++) rsum[mi][r] = 0.f;
#pragma unroll
    for (int mi = 0; mi < 2; mi++)
#pragma unroll
      for (int nj = 0; nj < 8; nj++)
#pragma unroll
        for (int r = 0; r < 4; r++) {
          float p = __expf(sc[mi][nj][r] - mrun[mi][r]);
          sc[mi][nj][r] = p;
          rsum[mi][r] += p;
        }
#pragma unroll
    for (int mi = 0; mi < 2; mi++)
#pragma unroll
      for (int r = 0; r < 4; r++) {
        float s = rsum[mi][r];
#pragma unroll
        for (int m = 1; m <= 8; m <<= 1) s += __shfl_xor(s, m);
        lrun[mi][r] = lrun[mi][r] * corr[mi][r] + s;
      }
#pragma unroll
    for (int mi = 0; mi < 2; mi++)
#pragma unroll
      for (int nj = 0; nj < 4; nj++)
#pragma unroll
        for (int r = 0; r < 4; r++) oacc[mi][nj][r] *= corr[mi][r];

#pragma unroll
    for (int mi = 0; mi < 2; mi++)
#pragma unroll
      for (int nj = 0; nj < 8; nj++)
#pragma unroll
        for (int r = 0; r < 4; r++)
          Ps[(w * 32 + mi * 16 + grp * 4 + r) * 144 + nj * 16 + l] = f2bf(sc[mi][nj][r]);
    __syncthreads();

#pragma unroll
    for (int ks = 0; ks < 4; ks++) {
      bf16x8 pf[2];
#pragma unroll
      for (int mi = 0; mi < 2; mi++)
        pf[mi] = *(const bf16x8*)(Ps + (w * 32 + mi * 16 + l) * 144 + ks * 32 + grp * 8);
      int s8 = ks * 4 + grp;
#pragma unroll
      for (int nj = 0; nj < 4; nj++) {
        int hd = nj * 16 + l;
        bf16x8 vf = *(const bf16x8*)(Vt + hd * 144 + ((s8 ^ (hd >> 2)) * 8));
#pragma unroll
        for (int mi = 0; mi < 2; mi++)
          oacc[mi][nj] = __builtin_amdgcn_mfma_f32_16x16x32_bf16(pf[mi], vf, oacc[mi][nj], 0, 0, 0);
      }
    }
  }

#pragma unroll
  for (int mi = 0; mi < 2; mi++)
#pragma unroll
    for (int nj = 0; nj < 4; nj++)
#pragma unroll
      for (int r = 0; r < 4; r++) {
        int qrow = q0 + w * 32 + mi * 16 + grp * 4 + r;
        int hd = nj * 16 + l;
        float v = oacc[mi][nj][r] / lrun[mi][r];
        ctx[(size_t)(b * SSEQ + qrow) * DDIM + h * HDIM + hd] = f2bf(v);
      }
}

// ----------------------------------------------------------------- swiglu
__global__ __launch_bounds__(256) void swiglu_kernel(
    const unsigned short* __restrict__ gu, unsigned short* __restrict__ a)
{
  size_t idx = ((size_t)blockIdx.x * 256 + threadIdx.x) * 8;
  int r = (int)(idx >> 13);
  int c = (int)(idx & 8191);
  const unsigned short* gp = gu + (size_t)r * (2 * IDIM) + c;
  us8 gv = *(const us8*)gp;
  us8 uv = *(const us8*)(gp + IDIM);
  us8 ov;
#pragma unroll
  for (int j = 0; j < 8; j++) {
    float g = bf2f(gv[j]), u = bf2f(uv[j]);
    ov[j] = f2bf(g / (1.f + __expf(-g)) * u);
  }
  *(us8*)(a + idx) = ov;
}

// ----------------------------------------------------------------- host
extern "C" void kernel_launch(void* const* d_in, const int* in_sizes, int n_in,
                              void* d_out, int out_size, void* d_ws, size_t ws_size,
                              hipStream_t stream) {
  (void)in_sizes; (void)n_in; (void)out_size; (void)ws_size;
  const float* hs    = (const float*)d_in[0];
  const int*   amask = (const int*)d_in[1];
  const float* ln1_g = (const float*)d_in[2];
  const float* ln1_b = (const float*)d_in[3];
  const float* qkv_w = (const float*)d_in[4];
  const float* o_w   = (const float*)d_in[5];
  const float* ln2_g = (const float*)d_in[6];
  const float* ln2_b = (const float*)d_in[7];
  const float* gu_w  = (const float*)d_in[8];
  const float* gu_b  = (const float*)d_in[9];
  const float* down_w = (const float*)d_in[10];
  const float* down_b = (const float*)d_in[11];
  float* out = (float*)d_out;

  char* ws = (char*)d_ws;
  unsigned short* Wt   = (unsigned short*)ws;                    // 64 MiB
  unsigned short* xb   = (unsigned short*)(ws + 67108864);       // 8 MiB
  unsigned short* qkvb = (unsigned short*)(ws + 75497472);       // 24 MiB
  unsigned short* ctxb = (unsigned short*)(ws + 100663296);      // 8 MiB
  unsigned short* gub  = (unsigned short*)(ws + 109051904);      // 64 MiB
  unsigned short* ab   = qkvb;          // alias (qkv dead after attn+o-proj A-read? no:
                                        // ab only written by swiglu, after ctx consumed)
  float* P = (float*)gub;               // split-K partials, 4x16MiB (gub dead then)

  hipError_t e0 = hipFuncSetAttribute(
      reinterpret_cast<const void*>(&gemm256_kernel<0>),
      hipFuncAttributeMaxDynamicSharedMemorySize, 131072);
  hipError_t e1 = hipFuncSetAttribute(
      reinterpret_cast<const void*>(&gemm256_kernel<1>),
      hipFuncAttributeMaxDynamicSharedMemorySize, 131072);
  bool use256 = (e0 == hipSuccess && e1 == hipSuccess);

  hipMemcpyAsync(out, hs, (size_t)MM * DDIM * sizeof(float),
                 hipMemcpyDeviceToDevice, stream);

  for (int lidx = 0; lidx < LNUM; lidx++) {
    // ---- LN1 (fused with previous layer's down-proj reduce if lidx>0)
    if (use256 && lidx > 0)
      ln_kernel<4><<<MM, 256, 0, stream>>>(out, P, down_b + (lidx - 1) * DDIM,
          ln1_g + lidx * DDIM, ln1_b + lidx * DDIM, xb);
    else
      ln_kernel<0><<<MM, 256, 0, stream>>>(out, nullptr, nullptr,
          ln1_g + lidx * DDIM, ln1_b + lidx * DDIM, xb);

    // ---- QKV
    cvt_t_kernel<<<dim3(DDIM / 32, (3 * DDIM) / 32), 256, 0, stream>>>(
        qkv_w + (size_t)lidx * DDIM * 3 * DDIM, Wt, DDIM, 3 * DDIM);
    if (use256)
      gemm256_kernel<0><<<dim3((3 * DDIM) / 256, MM / 256), 512, 131072, stream>>>(
          xb, Wt, qkvb, nullptr, nullptr, MM, 3 * DDIM, DDIM, DDIM);
    else
      gemm_kernel<0><<<dim3((3 * DDIM) / 128, MM / 128), 256, 0, stream>>>(
          xb, Wt, qkvb, nullptr, nullptr, MM, 3 * DDIM, DDIM);

    attn_kernel<<<dim3(SSEQ / 128, BBATCH * HHEADS), 256, 0, stream>>>(qkvb, amask, ctxb);

    // ---- O-proj: split-K=4 into partials, reduce fused into LN2
    cvt_t_kernel<<<dim3(DDIM / 32, DDIM / 32), 256, 0, stream>>>(
        o_w + (size_t)lidx * DDIM * DDIM, Wt, DDIM, DDIM);
    if (use256) {
      gemm256_kernel<1><<<dim3(DDIM / 256, MM / 256, 4), 512, 131072, stream>>>(
          ctxb, Wt, nullptr, P, nullptr, MM, DDIM, DDIM, DDIM / 4);
      ln_kernel<4><<<MM, 256, 0, stream>>>(out, P, nullptr,
          ln2_g + lidx * DDIM, ln2_b + lidx * DDIM, xb);
    } else {
      gemm_kernel<2><<<dim3(DDIM / 128, MM / 128), 256, 0, stream>>>(
          ctxb, Wt, nullptr, out, nullptr, MM, DDIM, DDIM);
      ln_kernel<0><<<MM, 256, 0, stream>>>(out, nullptr, nullptr,
          ln2_g + lidx * DDIM, ln2_b + lidx * DDIM, xb);
    }

    // ---- GU
    cvt_t_kernel<<<dim3(DDIM / 32, (2 * IDIM) / 32), 256, 0, stream>>>(
        gu_w + (size_t)lidx * DDIM * 2 * IDIM, Wt, DDIM, 2 * IDIM);
    if (use256)
      gemm256_kernel<0><<<dim3((2 * IDIM) / 256, MM / 256), 512, 131072, stream>>>(
          xb, Wt, gub, nullptr, gu_b + (size_t)lidx * 2 * IDIM, MM, 2 * IDIM, DDIM, DDIM);
    else
      gemm_kernel<0><<<dim3((2 * IDIM) / 128, MM / 128), 256, 0, stream>>>(
          xb, Wt, gub, nullptr, gu_b + (size_t)lidx * 2 * IDIM, MM, 2 * IDIM, DDIM);

    swiglu_kernel<<<(MM * IDIM / 8) / 256, 256, 0, stream>>>(gub, ab);

    // ---- Down: split-K=4 into partials (gub dead after swiglu)
    cvt_t_kernel<<<dim3(IDIM / 32, DDIM / 32), 256, 0, stream>>>(
        down_w + (size_t)lidx * IDIM * DDIM, Wt, IDIM, DDIM);
    if (use256) {
      gemm256_kernel<1><<<dim3(DDIM / 256, MM / 256, 4), 512, 131072, stream>>>(
          ab, Wt, nullptr, P, nullptr, MM, DDIM, IDIM, IDIM / 4);
      if (lidx == LNUM - 1)
        red_kernel<<<(MM * DDIM / 4) / 256, 256, 0, stream>>>(
            out, P, down_b + lidx * DDIM);
      // else: reduce fused into next layer's LN1
    } else {
      gemm_kernel<2><<<dim3(DDIM / 128, MM / 128), 256, 0, stream>>>(
          ab, Wt, nullptr, out, down_b + lidx * DDIM, MM, DDIM, IDIM);
    }
  }
}

// Round 4
// 952.203 us; speedup vs baseline: 1.4868x; 1.0858x over previous
//
#include <hip/hip_runtime.h>

#define LNUM 2
#define BBATCH 2
#define SSEQ 1024
#define DDIM 2048
#define HHEADS 32
#define HDIM 64
#define IDIM 8192
#define MM 2048   // B*S

typedef __attribute__((ext_vector_type(4))) float f32x4;
typedef __attribute__((ext_vector_type(8))) __bf16 bf16x8;
typedef __attribute__((ext_vector_type(4))) unsigned short us4;
typedef __attribute__((ext_vector_type(8))) unsigned short us8;

__device__ __forceinline__ unsigned short f2bf(float f) {
  union { float f; unsigned u; } v; v.f = f;
  unsigned r = v.u + 0x7fffu + ((v.u >> 16) & 1u);
  return (unsigned short)(r >> 16);
}
__device__ __forceinline__ float bf2f(unsigned short b) {
  union { unsigned u; float f; } v; v.u = ((unsigned)b) << 16;
  return v.f;
}

#define GLD16(g, l) __builtin_amdgcn_global_load_lds( \
    (const __attribute__((address_space(1))) void*)(g), \
    (__attribute__((address_space(3))) void*)(l), 16, 0, 0)

// ---------------------------------------------------------------- LayerNorm
// REDSPLIT=0: plain LN. REDSPLIT=4: x_row += sum of 4 fp32 partials (+rbias),
// write x back, then LN. fp32 in -> bf16 out.
template<int REDSPLIT>
__global__ __launch_bounds__(256) void ln_kernel(
    float* __restrict__ x, const float* __restrict__ part,
    const float* __restrict__ rbias,
    const float* __restrict__ g, const float* __restrict__ bta,
    unsigned short* __restrict__ out)
{
  int tid = threadIdx.x;
  int lane = tid & 63, w = tid >> 6;
  int row = blockIdx.x;
  float* xr = x + (size_t)row * DDIM;
  f32x4* xr4 = (f32x4*)xr;
  f32x4 v[2];
  float s1 = 0.f, s2 = 0.f;
#pragma unroll
  for (int i = 0; i < 2; i++) {
    int idx4 = tid + 256 * i;
    v[i] = xr4[idx4];
    if (REDSPLIT > 0) {
#pragma unroll
      for (int s = 0; s < REDSPLIT; s++) {
        f32x4 p = *(const f32x4*)(part + (size_t)s * MM * DDIM + (size_t)row * DDIM + idx4 * 4);
        v[i] += p;
      }
      if (rbias) {
        f32x4 bv = *(const f32x4*)(rbias + idx4 * 4);
        v[i] += bv;
      }
      xr4[idx4] = v[i];
    }
#pragma unroll
    for (int j = 0; j < 4; j++) { s1 += v[i][j]; s2 += v[i][j] * v[i][j]; }
  }
#pragma unroll
  for (int m = 1; m < 64; m <<= 1) {
    s1 += __shfl_xor(s1, m);
    s2 += __shfl_xor(s2, m);
  }
  __shared__ float red[8];
  if (lane == 0) { red[w * 2] = s1; red[w * 2 + 1] = s2; }
  __syncthreads();
  s1 = red[0] + red[2] + red[4] + red[6];
  s2 = red[1] + red[3] + red[5] + red[7];
  float mu = s1 / (float)DDIM;
  float var = s2 / (float)DDIM - mu * mu;
  float rstd = rsqrtf(var + 1e-5f);
#pragma unroll
  for (int i = 0; i < 2; i++) {
    int c0 = (tid + 256 * i) * 4;
    us4 o;
#pragma unroll
    for (int j = 0; j < 4; j++)
      o[j] = f2bf((v[i][j] - mu) * rstd * g[c0 + j] + bta[c0 + j]);
    *(us4*)(out + (size_t)row * DDIM + c0) = o;
  }
}

// --------------------------------------------------- final split-K reduce
__global__ __launch_bounds__(256) void red_kernel(
    float* __restrict__ out, const float* __restrict__ part,
    const float* __restrict__ bias)
{
  size_t i = (size_t)blockIdx.x * 256 + threadIdx.x;   // f32x4 index
  f32x4 o = ((f32x4*)out)[i];
#pragma unroll
  for (int s = 0; s < 4; s++)
    o += *(const f32x4*)(part + (size_t)s * MM * DDIM + i * 4);
  int col4 = (int)((i * 4) & (DDIM - 1));
  f32x4 bv = *(const f32x4*)(bias + col4);
  o += bv;
  ((f32x4*)out)[i] = o;
}

// ------------------------------------------------- weight convert+transpose
// PERM=0: Wt[n][k] = W[k][n].
// PERM=1 (gate/up interleave for fused swiglu): output row p holds orig col
//   perm(p) = (p>>5)*16 + (p&15) + ((p&16) ? N/2 : 0)
template<int PERM>
__global__ __launch_bounds__(256) void cvt_t_kernel(
    const float* __restrict__ W, unsigned short* __restrict__ Wt, int K, int N)
{
  __shared__ float tile[32][33];
  int t = threadIdx.x;
  int k0 = blockIdx.x << 5, n0 = blockIdx.y << 5;
  int r = t >> 3, c4 = (t & 7) << 2;
  int colbase;
  if (PERM == 1)
    colbase = (n0 >> 1) + (c4 & 15) + ((c4 & 16) ? (N >> 1) : 0);
  else
    colbase = n0 + c4;
  f32x4 v = *(const f32x4*)(W + (size_t)(k0 + r) * N + colbase);
  tile[r][c4 + 0] = v[0]; tile[r][c4 + 1] = v[1];
  tile[r][c4 + 2] = v[2]; tile[r][c4 + 3] = v[3];
  __syncthreads();
  us4 o;
#pragma unroll
  for (int j = 0; j < 4; j++) o[j] = f2bf(tile[c4 + j][r]);
  *(us4*)(Wt + (size_t)(n0 + r) * K + k0 + c4) = o;
}

// ----------------------------------------------------------------- 128^2 GEMM (fallback)
template<int OUTMODE>
__global__ __launch_bounds__(256) void gemm_kernel(
    const unsigned short* __restrict__ A, const unsigned short* __restrict__ Bt,
    unsigned short* __restrict__ outB, float* __restrict__ outF,
    const float* __restrict__ bias, int M, int N, int K)
{
  __shared__ unsigned short As[128 * 32];
  __shared__ unsigned short Bs[128 * 32];
  int tid = threadIdx.x;
  int lane = tid & 63, w = tid >> 6;
  int m0 = blockIdx.y * 128, n0 = blockIdx.x * 128;
  int wr = w >> 1, wc = w & 1;

  f32x4 z4 = {0.f, 0.f, 0.f, 0.f};
  f32x4 acc[4][4];
#pragma unroll
  for (int i = 0; i < 4; i++)
#pragma unroll
    for (int j = 0; j < 4; j++) acc[i][j] = z4;

  int bofs0 = w * 1024 + lane * 16;
  int bofs1 = (4 + w) * 1024 + lane * 16;
  int r0 = bofs0 >> 6, c0 = (bofs0 & 63) >> 1;
  int r1 = bofs1 >> 6, c1 = (bofs1 & 63) >> 1;
  const unsigned short* a0 = A + (size_t)(m0 + r0) * K + c0;
  const unsigned short* a1 = A + (size_t)(m0 + r1) * K + c1;
  const unsigned short* b0 = Bt + (size_t)(n0 + r0) * K + c0;
  const unsigned short* b1 = Bt + (size_t)(n0 + r1) * K + c1;
  unsigned short* lA0 = As + w * 512;
  unsigned short* lA1 = As + (4 + w) * 512;
  unsigned short* lB0 = Bs + w * 512;
  unsigned short* lB1 = Bs + (4 + w) * 512;

  int arow = wr * 64 + (lane & 15);
  int brow = wc * 64 + (lane & 15);
  int koff = (lane >> 4) * 8;

  for (int kt = 0; kt < K; kt += 32) {
    __syncthreads();
    GLD16(a0 + kt, lA0);
    GLD16(a1 + kt, lA1);
    GLD16(b0 + kt, lB0);
    GLD16(b1 + kt, lB1);
    __syncthreads();
    bf16x8 af[4], bfr[4];
#pragma unroll
    for (int i = 0; i < 4; i++)
      af[i] = *(const bf16x8*)(As + (arow + i * 16) * 32 + koff);
#pragma unroll
    for (int j = 0; j < 4; j++)
      bfr[j] = *(const bf16x8*)(Bs + (brow + j * 16) * 32 + koff);
#pragma unroll
    for (int i = 0; i < 4; i++)
#pragma unroll
      for (int j = 0; j < 4; j++)
        acc[i][j] = __builtin_amdgcn_mfma_f32_16x16x32_bf16(af[i], bfr[j], acc[i][j], 0, 0, 0);
  }

  int grp = lane >> 4, l = lane & 15;
#pragma unroll
  for (int mi = 0; mi < 4; mi++) {
#pragma unroll
    for (int nj = 0; nj < 4; nj++) {
      int col = n0 + wc * 64 + nj * 16 + l;
      float bv = bias ? bias[col] : 0.f;
#pragma unroll
      for (int r = 0; r < 4; r++) {
        int row = m0 + wr * 64 + mi * 16 + grp * 4 + r;
        float v = acc[mi][nj][r] + bv;
        if (OUTMODE == 2) outF[(size_t)row * N + col] += v;
        else outB[(size_t)row * N + col] = f2bf(v);
      }
    }
  }
}

// ----------------------------------------------------------------- 256^2 8-phase GEMM
// OUTMODE 0: bf16 out (+bias). OUTMODE 1: fp32 split-K partial at outF+z*M*N.
// OUTMODE 3: fused swiglu (interleaved gate/up cols; writes bf16 [M][N/2]).
#define BAR __builtin_amdgcn_s_barrier()
#define SCHED0 __builtin_amdgcn_sched_barrier(0)
#define LGKM0 { asm volatile("s_waitcnt lgkmcnt(0)" ::: "memory"); SCHED0; }
#define VMC4 { asm volatile("s_waitcnt vmcnt(4)" ::: "memory"); SCHED0; }
#define VMC0 { asm volatile("s_waitcnt vmcnt(0)" ::: "memory"); SCHED0; }

#define STG_A(p,h,t) { \
  GLD16(pA[h][0] + (size_t)(t)*64, smem + ldsA + (p)*32768 + (h)*16384); \
  GLD16(pA[h][1] + (size_t)(t)*64, smem + ldsA + (p)*32768 + (h)*16384 + 8192); }
#define STG_B(p,h,t) { \
  GLD16(pB[h][0] + (size_t)(t)*64, smem + ldsB + (p)*32768 + (h)*16384); \
  GLD16(pB[h][1] + (size_t)(t)*64, smem + ldsB + (p)*32768 + (h)*16384 + 8192); }

#define DSR_A(p, misel, ks) { \
  _Pragma("unroll") \
  for (int mi = 0; mi < 4; mi++) \
    af[mi] = *(const bf16x8*)(smem + (p)*32768 + aRd + ((misel)*64 + mi*16)*128 + ch[ks]); }
#define DSR_B(p, ks) { \
  _Pragma("unroll") \
  for (int nj = 0; nj < 4; nj++) \
    bfr[ks][nj] = *(const bf16x8*)(smem + (p)*32768 + bRd + nj*2048 + ch[ks]); }

#define MFMA16(misel, ks) { \
  _Pragma("unroll") \
  for (int mi = 0; mi < 4; mi++) \
    _Pragma("unroll") \
    for (int nj = 0; nj < 4; nj++) \
      acc[(misel)*4+mi][nj] = __builtin_amdgcn_mfma_f32_16x16x32_bf16( \
          af[mi], bfr[ks][nj], acc[(misel)*4+mi][nj], 0, 0, 0); }

#define TILE(p, t) { \
  DSR_A(p, 0, 0); DSR_B(p, 0); \
  if ((t)+1 < NT) STG_A(1-(p), 0, (t)+1); \
  SCHED0; BAR; LGKM0; \
  __builtin_amdgcn_s_setprio(1); MFMA16(0, 0); __builtin_amdgcn_s_setprio(0); \
  SCHED0; BAR; \
  DSR_A(p, 0, 1); DSR_B(p, 1); \
  if ((t)+1 < NT) STG_A(1-(p), 1, (t)+1); \
  SCHED0; BAR; LGKM0; \
  __builtin_amdgcn_s_setprio(1); MFMA16(0, 1); __builtin_amdgcn_s_setprio(0); \
  SCHED0; BAR; \
  DSR_A(p, 1, 0); \
  if ((t)+2 < NT) STG_B(p, 0, (t)+2); \
  SCHED0; BAR; LGKM0; \
  __builtin_amdgcn_s_setprio(1); MFMA16(1, 0); __builtin_amdgcn_s_setprio(0); \
  SCHED0; BAR; \
  DSR_A(p, 1, 1); \
  if ((t)+2 < NT) STG_B(p, 1, (t)+2); \
  SCHED0; BAR; LGKM0; \
  __builtin_amdgcn_s_setprio(1); MFMA16(1, 1); __builtin_amdgcn_s_setprio(0); \
  if ((t)+2 < NT) { VMC4; } else { VMC0; } \
  SCHED0; BAR; }

template<int OUTMODE>
__global__ __launch_bounds__(512, 2) void gemm256_kernel(
    const unsigned short* __restrict__ A, const unsigned short* __restrict__ Bt,
    unsigned short* __restrict__ outB, float* __restrict__ outF,
    const float* __restrict__ bias, int M, int N, int Kstride, int Kc)
{
  extern __shared__ char smem[];  // A: [2][256][128B] @0; B: same @65536
  int tid = threadIdx.x;
  int lane = tid & 63, w = tid >> 6;
  int wr = w >> 2, wc = w & 3;
  int l15 = lane & 15, grp = lane >> 4;

  int nwg = gridDim.x * gridDim.y;
  int bid = blockIdx.y * gridDim.x + blockIdx.x;
  int cpx = nwg >> 3;
  int sw = (bid & 7) * cpx + (bid >> 3);
  int bx = sw % gridDim.x, by = sw / gridDim.x;
  int m0 = by * 256, n0 = bx * 256;

  int NT = Kc >> 6;
  const unsigned short* Az = A  + (size_t)blockIdx.z * Kc;
  const unsigned short* Bz = Bt + (size_t)blockIdx.z * Kc;

  int srow = lane >> 3;
  int kcol = ((lane & 7) ^ srow) * 8;
  const unsigned short* pA[2][2];
  const unsigned short* pB[2][2];
#pragma unroll
  for (int h = 0; h < 2; h++)
#pragma unroll
    for (int i = 0; i < 2; i++) {
      pA[h][i] = Az + (size_t)(m0 + h*128 + i*64 + w*8 + srow) * Kstride + kcol;
      pB[h][i] = Bz + (size_t)(n0 + h*128 + i*64 + w*8 + srow) * Kstride + kcol;
    }
  int ldsA = w*1024 + lane*16;
  int ldsB = 65536 + w*1024 + lane*16;

  int aRd = (wr*128 + l15) * 128;
  int bRd = 65536 + (wc*64 + l15) * 128;
  int ch[2];
  ch[0] = ((0*4 + grp) ^ (l15 & 7)) * 16;
  ch[1] = ((1*4 + grp) ^ (l15 & 7)) * 16;

  f32x4 z4 = {0.f, 0.f, 0.f, 0.f};
  f32x4 acc[8][4];
#pragma unroll
  for (int i = 0; i < 8; i++)
#pragma unroll
    for (int j = 0; j < 4; j++) acc[i][j] = z4;
  bf16x8 af[4];
  bf16x8 bfr[2][4];

  STG_A(0, 0, 0); STG_A(0, 1, 0); STG_B(0, 0, 0); STG_B(0, 1, 0);
  if (NT > 1) { STG_B(1, 0, 1); STG_B(1, 1, 1); VMC4; } else { VMC0; }
  BAR;

  for (int t = 0; t < NT; t += 2) {   // NT even for all uses (8/24/32)
    TILE(0, t);
    TILE(1, t + 1);
  }

  if (OUTMODE == 3) {
    // interleaved gate/up: nj pairs (0,1)=gate/up of cols cbase/2 + l15,
    // (2,3)=cols cbase/2+16+l15. Output width N/2.
    int cbase = n0 + wc * 64;
    int half = N >> 1;
#pragma unroll
    for (int mi = 0; mi < 8; mi++) {
#pragma unroll
      for (int p = 0; p < 2; p++) {
        int jcol = (cbase >> 1) + p * 16 + l15;
        float bg = bias[jcol];
        float bu = bias[half + jcol];
#pragma unroll
        for (int r = 0; r < 4; r++) {
          int row = m0 + wr * 128 + mi * 16 + grp * 4 + r;
          float g = acc[mi][2 * p][r] + bg;
          float u = acc[mi][2 * p + 1][r] + bu;
          float sv = g / (1.f + __expf(-g)) * u;
          outB[(size_t)row * half + jcol] = f2bf(sv);
        }
      }
    }
  } else {
#pragma unroll
    for (int mi = 0; mi < 8; mi++) {
#pragma unroll
      for (int nj = 0; nj < 4; nj++) {
        int col = n0 + wc * 64 + nj * 16 + l15;
        float bv = (OUTMODE == 0 && bias) ? bias[col] : 0.f;
#pragma unroll
        for (int r = 0; r < 4; r++) {
          int row = m0 + wr * 128 + mi * 16 + grp * 4 + r;
          float v = acc[mi][nj][r] + bv;
          if (OUTMODE == 1)
            outF[(size_t)blockIdx.z * M * N + (size_t)row * N + col] = v;
          else
            outB[(size_t)row * N + col] = f2bf(v);
        }
      }
    }
  }
}

// ----------------------------------------------------------- attention
// 2 blocks/CU (LDS 79872B). PV in two half-passes (Ps [128][80]).
__global__ __launch_bounds__(256) void attn_kernel(
    const unsigned short* __restrict__ qkv, const int* __restrict__ amask,
    unsigned short* __restrict__ ctx)
{
  __shared__ unsigned short Qs[128 * 80];
  __shared__ unsigned short Ks[128 * 80];
  __shared__ unsigned short Vt[64 * 144];
  __shared__ unsigned short Ps[128 * 80];

  int tid = threadIdx.x, lane = tid & 63, w = tid >> 6;
  int grp = lane >> 4, l = lane & 15;
  int q0 = blockIdx.x * 128;
  int bh = blockIdx.y;
  int b = bh >> 5, h = bh & 31;
  const size_t rs = 3 * DDIM;
  const unsigned short* qbase = qkv + (size_t)(b * SSEQ) * rs + h * HDIM;
  const unsigned short* kbase = qbase + DDIM;
  const unsigned short* vbase = qbase + 2 * DDIM;

#pragma unroll
  for (int i = 0; i < 4; i++) {
    int c = tid + 256 * i;
    int r = c >> 3, part = c & 7;
    us8 v = *(const us8*)(qbase + (size_t)(q0 + r) * rs + part * 8);
    *(us8*)(Qs + r * 80 + part * 8) = v;
  }

  float mrun[2][4], lrun[2][4];
  f32x4 z4 = {0.f, 0.f, 0.f, 0.f};
  f32x4 oacc[2][4];
#pragma unroll
  for (int mi = 0; mi < 2; mi++)
#pragma unroll
    for (int r = 0; r < 4; r++) { mrun[mi][r] = -1e30f; lrun[mi][r] = 0.f; }
#pragma unroll
  for (int mi = 0; mi < 2; mi++)
#pragma unroll
    for (int nj = 0; nj < 4; nj++) oacc[mi][nj] = z4;

  for (int kb = 0; kb < 8; kb++) {
    // stage K tile (prev iter's reads of Ks/Vt are behind the h=1 trailing sync)
#pragma unroll
    for (int i = 0; i < 4; i++) {
      int c = tid + 256 * i;
      int r = c >> 3, part = c & 7;
      us8 v = *(const us8*)(kbase + (size_t)(kb * 128 + r) * rs + part * 8);
      *(us8*)(Ks + r * 80 + part * 8) = v;
    }
#pragma unroll
    for (int i = 0; i < 2; i++) {
      int bb = tid + 256 * i;
      int hb = bb & 15, sb = bb >> 4;
      int hd0 = hb * 4, s0 = sb * 4;
      us4 rv[4];
#pragma unroll
      for (int j = 0; j < 4; j++)
        rv[j] = *(const us4*)(vbase + (size_t)(kb * 128 + s0 + j) * rs + hd0);
      int s8 = s0 >> 3, rem = s0 & 7;
#pragma unroll
      for (int j2 = 0; j2 < 4; j2++) {
        int hd = hd0 + j2;
        us4 ov;
        ov[0] = rv[0][j2]; ov[1] = rv[1][j2]; ov[2] = rv[2][j2]; ov[3] = rv[3][j2];
        *(us4*)(Vt + hd * 144 + ((s8 ^ (hd >> 2)) * 8) + rem) = ov;
      }
    }
    __syncthreads();

    f32x4 sc[2][8];
#pragma unroll
    for (int mi = 0; mi < 2; mi++)
#pragma unroll
      for (int nj = 0; nj < 8; nj++) sc[mi][nj] = z4;
    __builtin_amdgcn_s_setprio(1);
#pragma unroll
    for (int ks = 0; ks < 2; ks++) {
      bf16x8 aq[2];
#pragma unroll
      for (int mi = 0; mi < 2; mi++)
        aq[mi] = *(const bf16x8*)(Qs + (w * 32 + mi * 16 + l) * 80 + ks * 32 + grp * 8);
#pragma unroll
      for (int nj = 0; nj < 8; nj++) {
        bf16x8 bk = *(const bf16x8*)(Ks + (nj * 16 + l) * 80 + ks * 32 + grp * 8);
#pragma unroll
        for (int mi = 0; mi < 2; mi++)
          sc[mi][nj] = __builtin_amdgcn_mfma_f32_16x16x32_bf16(aq[mi], bk, sc[mi][nj], 0, 0, 0);
      }
    }
    __builtin_amdgcn_s_setprio(0);
    float mb[8];
#pragma unroll
    for (int nj = 0; nj < 8; nj++) {
      int col = kb * 128 + nj * 16 + l;
      mb[nj] = (1.0f - (float)amask[b * SSEQ + col]) * -10000.0f;
    }
#pragma unroll
    for (int mi = 0; mi < 2; mi++)
#pragma unroll
      for (int nj = 0; nj < 8; nj++)
#pragma unroll
        for (int r = 0; r < 4; r++)
          sc[mi][nj][r] = sc[mi][nj][r] * 0.125f + mb[nj];

    float pm[2][4];
#pragma unroll
    for (int mi = 0; mi < 2; mi++)
#pragma unroll
      for (int r = 0; r < 4; r++) {
        float m = sc[mi][0][r];
#pragma unroll
        for (int nj = 1; nj < 8; nj++) m = fmaxf(m, sc[mi][nj][r]);
#pragma unroll
        for (int s = 1; s <= 8; s <<= 1) m = fmaxf(m, __shfl_xor(m, s));
        pm[mi][r] = m;
      }
    float corr[2][4];
#pragma unroll
    for (int mi = 0; mi < 2; mi++)
#pragma unroll
      for (int r = 0; r < 4; r++) {
        float nm = fmaxf(mrun[mi][r], pm[mi][r]);
        corr[mi][r] = __expf(mrun[mi][r] - nm);
        mrun[mi][r] = nm;
      }
    float rsum[2][4];
#pragma unroll
    for (int mi = 0; mi < 2; mi++)
#pragma unroll
      for (int r = 0; r < 4; r++) rsum[mi][r] = 0.f;
#pragma unroll
    for (int mi = 0; mi < 2; mi++)
#pragma unroll
      for (int nj = 0; nj < 8; nj++)
#pragma unroll
        for (int r = 0; r < 4; r++) {
          float p = __expf(sc[mi][nj][r] - mrun[mi][r]);
          sc[mi][nj][r] = p;
          rsum[mi][r] += p;
        }
#pragma unroll
    for (int mi = 0; mi < 2; mi++)
#pragma unroll
      for (int r = 0; r < 4; r++) {
        float s = rsum[mi][r];
#pragma unroll
        for (int m = 1; m <= 8; m <<= 1) s += __shfl_xor(s, m);
        lrun[mi][r] = lrun[mi][r] * corr[mi][r] + s;
      }
#pragma unroll
    for (int mi = 0; mi < 2; mi++)
#pragma unroll
      for (int nj = 0; nj < 4; nj++)
#pragma unroll
        for (int r = 0; r < 4; r++) oacc[mi][nj][r] *= corr[mi][r];

    // PV in two half-passes over the 128 key-cols
#pragma unroll
    for (int h2 = 0; h2 < 2; h2++) {
#pragma unroll
      for (int mi = 0; mi < 2; mi++)
#pragma unroll
        for (int njl = 0; njl < 4; njl++)
#pragma unroll
          for (int r = 0; r < 4; r++)
            Ps[(w * 32 + mi * 16 + grp * 4 + r) * 80 + njl * 16 + l] =
                f2bf(sc[mi][h2 * 4 + njl][r]);
      __syncthreads();
      __builtin_amdgcn_s_setprio(1);
#pragma unroll
      for (int ksl = 0; ksl < 2; ksl++) {
        bf16x8 pf[2];
#pragma unroll
        for (int mi = 0; mi < 2; mi++)
          pf[mi] = *(const bf16x8*)(Ps + (w * 32 + mi * 16 + l) * 80 + ksl * 32 + grp * 8);
        int s8 = (h2 * 2 + ksl) * 4 + grp;
#pragma unroll
        for (int nj = 0; nj < 4; nj++) {
          int hd = nj * 16 + l;
          bf16x8 vf = *(const bf16x8*)(Vt + hd * 144 + ((s8 ^ (hd >> 2)) * 8));
#pragma unroll
          for (int mi = 0; mi < 2; mi++)
            oacc[mi][nj] = __builtin_amdgcn_mfma_f32_16x16x32_bf16(pf[mi], vf, oacc[mi][nj], 0, 0, 0);
        }
      }
      __builtin_amdgcn_s_setprio(0);
      __syncthreads();
    }
  }

#pragma unroll
  for (int mi = 0; mi < 2; mi++)
#pragma unroll
    for (int nj = 0; nj < 4; nj++)
#pragma unroll
      for (int r = 0; r < 4; r++) {
        int qrow = q0 + w * 32 + mi * 16 + grp * 4 + r;
        int hd = nj * 16 + l;
        float v = oacc[mi][nj][r] / lrun[mi][r];
        ctx[(size_t)(b * SSEQ + qrow) * DDIM + h * HDIM + hd] = f2bf(v);
      }
}

// ----------------------------------------------------------------- swiglu (fallback only)
__global__ __launch_bounds__(256) void swiglu_kernel(
    const unsigned short* __restrict__ gu, unsigned short* __restrict__ a)
{
  size_t idx = ((size_t)blockIdx.x * 256 + threadIdx.x) * 8;
  int r = (int)(idx >> 13);
  int c = (int)(idx & 8191);
  const unsigned short* gp = gu + (size_t)r * (2 * IDIM) + c;
  us8 gv = *(const us8*)gp;
  us8 uv = *(const us8*)(gp + IDIM);
  us8 ov;
#pragma unroll
  for (int j = 0; j < 8; j++) {
    float g = bf2f(gv[j]), u = bf2f(uv[j]);
    ov[j] = f2bf(g / (1.f + __expf(-g)) * u);
  }
  *(us8*)(a + idx) = ov;
}

// ----------------------------------------------------------------- host
extern "C" void kernel_launch(void* const* d_in, const int* in_sizes, int n_in,
                              void* d_out, int out_size, void* d_ws, size_t ws_size,
                              hipStream_t stream) {
  (void)in_sizes; (void)n_in; (void)out_size; (void)ws_size;
  const float* hs    = (const float*)d_in[0];
  const int*   amask = (const int*)d_in[1];
  const float* ln1_g = (const float*)d_in[2];
  const float* ln1_b = (const float*)d_in[3];
  const float* qkv_w = (const float*)d_in[4];
  const float* o_w   = (const float*)d_in[5];
  const float* ln2_g = (const float*)d_in[6];
  const float* ln2_b = (const float*)d_in[7];
  const float* gu_w  = (const float*)d_in[8];
  const float* gu_b  = (const float*)d_in[9];
  const float* down_w = (const float*)d_in[10];
  const float* down_b = (const float*)d_in[11];
  float* out = (float*)d_out;

  char* ws = (char*)d_ws;
  unsigned short* Wt   = (unsigned short*)ws;                    // 64 MiB
  unsigned short* xb   = (unsigned short*)(ws + 67108864);       // 8 MiB
  unsigned short* qkvb = (unsigned short*)(ws + 75497472);       // 24 MiB
  unsigned short* ctxb = (unsigned short*)(ws + 100663296);      // 8 MiB
  unsigned short* gub  = (unsigned short*)(ws + 109051904);      // 64 MiB (fallback gu / split-K partials)
  unsigned short* ab   = qkvb;          // [2048][8192] bf16 = 32 MiB over qkvb+ctxb (dead then)
  float* P = (float*)gub;               // split-K partials, 4x16 MiB

  hipError_t e0 = hipFuncSetAttribute(
      reinterpret_cast<const void*>(&gemm256_kernel<0>),
      hipFuncAttributeMaxDynamicSharedMemorySize, 131072);
  hipError_t e1 = hipFuncSetAttribute(
      reinterpret_cast<const void*>(&gemm256_kernel<1>),
      hipFuncAttributeMaxDynamicSharedMemorySize, 131072);
  hipError_t e3 = hipFuncSetAttribute(
      reinterpret_cast<const void*>(&gemm256_kernel<3>),
      hipFuncAttributeMaxDynamicSharedMemorySize, 131072);
  bool use256 = (e0 == hipSuccess && e1 == hipSuccess && e3 == hipSuccess);

  hipMemcpyAsync(out, hs, (size_t)MM * DDIM * sizeof(float),
                 hipMemcpyDeviceToDevice, stream);

  for (int lidx = 0; lidx < LNUM; lidx++) {
    // ---- LN1 (fused with previous layer's down-proj reduce if lidx>0)
    if (use256 && lidx > 0)
      ln_kernel<4><<<MM, 256, 0, stream>>>(out, P, down_b + (lidx - 1) * DDIM,
          ln1_g + lidx * DDIM, ln1_b + lidx * DDIM, xb);
    else
      ln_kernel<0><<<MM, 256, 0, stream>>>(out, nullptr, nullptr,
          ln1_g + lidx * DDIM, ln1_b + lidx * DDIM, xb);

    // ---- QKV
    cvt_t_kernel<0><<<dim3(DDIM / 32, (3 * DDIM) / 32), 256, 0, stream>>>(
        qkv_w + (size_t)lidx * DDIM * 3 * DDIM, Wt, DDIM, 3 * DDIM);
    if (use256)
      gemm256_kernel<0><<<dim3((3 * DDIM) / 256, MM / 256), 512, 131072, stream>>>(
          xb, Wt, qkvb, nullptr, nullptr, MM, 3 * DDIM, DDIM, DDIM);
    else
      gemm_kernel<0><<<dim3((3 * DDIM) / 128, MM / 128), 256, 0, stream>>>(
          xb, Wt, qkvb, nullptr, nullptr, MM, 3 * DDIM, DDIM);

    attn_kernel<<<dim3(SSEQ / 128, BBATCH * HHEADS), 256, 0, stream>>>(qkvb, amask, ctxb);

    // ---- O-proj: split-K=4 into partials, reduce fused into LN2
    cvt_t_kernel<0><<<dim3(DDIM / 32, DDIM / 32), 256, 0, stream>>>(
        o_w + (size_t)lidx * DDIM * DDIM, Wt, DDIM, DDIM);
    if (use256) {
      gemm256_kernel<1><<<dim3(DDIM / 256, MM / 256, 4), 512, 131072, stream>>>(
          ctxb, Wt, nullptr, P, nullptr, MM, DDIM, DDIM, DDIM / 4);
      ln_kernel<4><<<MM, 256, 0, stream>>>(out, P, nullptr,
          ln2_g + lidx * DDIM, ln2_b + lidx * DDIM, xb);
    } else {
      gemm_kernel<2><<<dim3(DDIM / 128, MM / 128), 256, 0, stream>>>(
          ctxb, Wt, nullptr, out, nullptr, MM, DDIM, DDIM);
      ln_kernel<0><<<MM, 256, 0, stream>>>(out, nullptr, nullptr,
          ln2_g + lidx * DDIM, ln2_b + lidx * DDIM, xb);
    }

    // ---- GU (+fused swiglu when use256): writes ab directly
    if (use256) {
      cvt_t_kernel<1><<<dim3(DDIM / 32, (2 * IDIM) / 32), 256, 0, stream>>>(
          gu_w + (size_t)lidx * DDIM * 2 * IDIM, Wt, DDIM, 2 * IDIM);
      gemm256_kernel<3><<<dim3((2 * IDIM) / 256, MM / 256), 512, 131072, stream>>>(
          xb, Wt, ab, nullptr, gu_b + (size_t)lidx * 2 * IDIM, MM, 2 * IDIM, DDIM, DDIM);
    } else {
      cvt_t_kernel<0><<<dim3(DDIM / 32, (2 * IDIM) / 32), 256, 0, stream>>>(
          gu_w + (size_t)lidx * DDIM * 2 * IDIM, Wt, DDIM, 2 * IDIM);
      gemm_kernel<0><<<dim3((2 * IDIM) / 128, MM / 128), 256, 0, stream>>>(
          xb, Wt, gub, nullptr, gu_b + (size_t)lidx * 2 * IDIM, MM, 2 * IDIM, DDIM);
      swiglu_kernel<<<(MM * IDIM / 8) / 256, 256, 0, stream>>>(gub, ab);
    }

    // ---- Down: split-K=4 into partials
    cvt_t_kernel<0><<<dim3(IDIM / 32, DDIM / 32), 256, 0, stream>>>(
        down_w + (size_t)lidx * IDIM * DDIM, Wt, IDIM, DDIM);
    if (use256) {
      gemm256_kernel<1><<<dim3(DDIM / 256, MM / 256, 4), 512, 131072, stream>>>(
          ab, Wt, nullptr, P, nullptr, MM, DDIM, IDIM, IDIM / 4);
      if (lidx == LNUM - 1)
        red_kernel<<<(MM * DDIM / 4) / 256, 256, 0, stream>>>(
            out, P, down_b + lidx * DDIM);
      // else: reduce fused into next layer's LN1
    } else {
      gemm_kernel<2><<<dim3(DDIM / 128, MM / 128), 256, 0, stream>>>(
          ab, Wt, nullptr, out, down_b + lidx * DDIM, MM, DDIM, IDIM);
    }
  }
}

// Round 5
// 911.223 us; speedup vs baseline: 1.5537x; 1.0450x over previous
//
#include <hip/hip_runtime.h>

#define LNUM 2
#define BBATCH 2
#define SSEQ 1024
#define DDIM 2048
#define HHEADS 32
#define HDIM 64
#define IDIM 8192
#define MM 2048   // B*S

typedef __attribute__((ext_vector_type(4))) float f32x4;
typedef __attribute__((ext_vector_type(8))) __bf16 bf16x8;
typedef __attribute__((ext_vector_type(4))) unsigned short us4;
typedef __attribute__((ext_vector_type(8))) unsigned short us8;

__device__ __forceinline__ unsigned short f2bf(float f) {
  union { float f; unsigned u; } v; v.f = f;
  unsigned r = v.u + 0x7fffu + ((v.u >> 16) & 1u);
  return (unsigned short)(r >> 16);
}
__device__ __forceinline__ float bf2f(unsigned short b) {
  union { unsigned u; float f; } v; v.u = ((unsigned)b) << 16;
  return v.f;
}

#define GLD16(g, l) __builtin_amdgcn_global_load_lds( \
    (const __attribute__((address_space(1))) void*)(g), \
    (__attribute__((address_space(3))) void*)(l), 16, 0, 0)

// ---------------------------------------------------------------- LayerNorm
// REDSPLIT=0: plain LN. REDSPLIT=4: x_row += sum of 4 bf16 partial rows
// (+rbias), write x back, then LN. fp32 in -> bf16 out.
template<int REDSPLIT>
__global__ __launch_bounds__(256) void ln_kernel(
    float* __restrict__ x, const unsigned short* __restrict__ part,
    const float* __restrict__ rbias,
    const float* __restrict__ g, const float* __restrict__ bta,
    unsigned short* __restrict__ out)
{
  int tid = threadIdx.x;
  int lane = tid & 63, w = tid >> 6;
  int row = blockIdx.x;
  float* xr = x + (size_t)row * DDIM;
  f32x4* xr4 = (f32x4*)xr;
  f32x4 v[2];
  float s1 = 0.f, s2 = 0.f;
#pragma unroll
  for (int i = 0; i < 2; i++) {
    int idx4 = tid + 256 * i;
    v[i] = xr4[idx4];
    if (REDSPLIT > 0) {
#pragma unroll
      for (int s = 0; s < REDSPLIT; s++) {
        us4 p = *(const us4*)(part + (size_t)s * MM * DDIM + (size_t)row * DDIM + idx4 * 4);
#pragma unroll
        for (int j = 0; j < 4; j++) v[i][j] += bf2f(p[j]);
      }
      if (rbias) {
        f32x4 bv = *(const f32x4*)(rbias + idx4 * 4);
        v[i] += bv;
      }
      xr4[idx4] = v[i];
    }
#pragma unroll
    for (int j = 0; j < 4; j++) { s1 += v[i][j]; s2 += v[i][j] * v[i][j]; }
  }
#pragma unroll
  for (int m = 1; m < 64; m <<= 1) {
    s1 += __shfl_xor(s1, m);
    s2 += __shfl_xor(s2, m);
  }
  __shared__ float red[8];
  if (lane == 0) { red[w * 2] = s1; red[w * 2 + 1] = s2; }
  __syncthreads();
  s1 = red[0] + red[2] + red[4] + red[6];
  s2 = red[1] + red[3] + red[5] + red[7];
  float mu = s1 / (float)DDIM;
  float var = s2 / (float)DDIM - mu * mu;
  float rstd = rsqrtf(var + 1e-5f);
#pragma unroll
  for (int i = 0; i < 2; i++) {
    int c0 = (tid + 256 * i) * 4;
    us4 o;
#pragma unroll
    for (int j = 0; j < 4; j++)
      o[j] = f2bf((v[i][j] - mu) * rstd * g[c0 + j] + bta[c0 + j]);
    *(us4*)(out + (size_t)row * DDIM + c0) = o;
  }
}

// --------------------------------------------------- final split-K reduce
__global__ __launch_bounds__(256) void red_kernel(
    float* __restrict__ out, const unsigned short* __restrict__ part,
    const float* __restrict__ bias)
{
  size_t i = (size_t)blockIdx.x * 256 + threadIdx.x;   // f32x4 index
  f32x4 o = ((f32x4*)out)[i];
#pragma unroll
  for (int s = 0; s < 4; s++) {
    us4 p = *(const us4*)(part + (size_t)s * MM * DDIM + i * 4);
#pragma unroll
    for (int j = 0; j < 4; j++) o[j] += bf2f(p[j]);
  }
  int col4 = (int)((i * 4) & (DDIM - 1));
  f32x4 bv = *(const f32x4*)(bias + col4);
  o += bv;
  ((f32x4*)out)[i] = o;
}

// ------------------------------------------------- weight convert+transpose
// PERM=0: Wt[n][k] = W[k][n].
// PERM=1 (gate/up interleave for fused swiglu): output row p holds orig col
//   perm(p) = (p>>5)*16 + (p&15) + ((p&16) ? N/2 : 0)
template<int PERM>
__global__ __launch_bounds__(256) void cvt_t_kernel(
    const float* __restrict__ W, unsigned short* __restrict__ Wt, int K, int N)
{
  __shared__ float tile[32][33];
  int t = threadIdx.x;
  int k0 = blockIdx.x << 5, n0 = blockIdx.y << 5;
  int r = t >> 3, c4 = (t & 7) << 2;
  int colbase;
  if (PERM == 1)
    colbase = (n0 >> 1) + (c4 & 15) + ((c4 & 16) ? (N >> 1) : 0);
  else
    colbase = n0 + c4;
  f32x4 v = *(const f32x4*)(W + (size_t)(k0 + r) * N + colbase);
  tile[r][c4 + 0] = v[0]; tile[r][c4 + 1] = v[1];
  tile[r][c4 + 2] = v[2]; tile[r][c4 + 3] = v[3];
  __syncthreads();
  us4 o;
#pragma unroll
  for (int j = 0; j < 4; j++) o[j] = f2bf(tile[c4 + j][r]);
  *(us4*)(Wt + (size_t)(n0 + r) * K + k0 + c4) = o;
}

// ----------------------------------------------------------------- 128^2 GEMM (fallback)
template<int OUTMODE>
__global__ __launch_bounds__(256) void gemm_kernel(
    const unsigned short* __restrict__ A, const unsigned short* __restrict__ Bt,
    unsigned short* __restrict__ outB, float* __restrict__ outF,
    const float* __restrict__ bias, int M, int N, int K)
{
  __shared__ unsigned short As[128 * 32];
  __shared__ unsigned short Bs[128 * 32];
  int tid = threadIdx.x;
  int lane = tid & 63, w = tid >> 6;
  int m0 = blockIdx.y * 128, n0 = blockIdx.x * 128;
  int wr = w >> 1, wc = w & 1;

  f32x4 z4 = {0.f, 0.f, 0.f, 0.f};
  f32x4 acc[4][4];
#pragma unroll
  for (int i = 0; i < 4; i++)
#pragma unroll
    for (int j = 0; j < 4; j++) acc[i][j] = z4;

  int bofs0 = w * 1024 + lane * 16;
  int bofs1 = (4 + w) * 1024 + lane * 16;
  int r0 = bofs0 >> 6, c0 = (bofs0 & 63) >> 1;
  int r1 = bofs1 >> 6, c1 = (bofs1 & 63) >> 1;
  const unsigned short* a0 = A + (size_t)(m0 + r0) * K + c0;
  const unsigned short* a1 = A + (size_t)(m0 + r1) * K + c1;
  const unsigned short* b0 = Bt + (size_t)(n0 + r0) * K + c0;
  const unsigned short* b1 = Bt + (size_t)(n0 + r1) * K + c1;
  unsigned short* lA0 = As + w * 512;
  unsigned short* lA1 = As + (4 + w) * 512;
  unsigned short* lB0 = Bs + w * 512;
  unsigned short* lB1 = Bs + (4 + w) * 512;

  int arow = wr * 64 + (lane & 15);
  int brow = wc * 64 + (lane & 15);
  int koff = (lane >> 4) * 8;

  for (int kt = 0; kt < K; kt += 32) {
    __syncthreads();
    GLD16(a0 + kt, lA0);
    GLD16(a1 + kt, lA1);
    GLD16(b0 + kt, lB0);
    GLD16(b1 + kt, lB1);
    __syncthreads();
    bf16x8 af[4], bfr[4];
#pragma unroll
    for (int i = 0; i < 4; i++)
      af[i] = *(const bf16x8*)(As + (arow + i * 16) * 32 + koff);
#pragma unroll
    for (int j = 0; j < 4; j++)
      bfr[j] = *(const bf16x8*)(Bs + (brow + j * 16) * 32 + koff);
#pragma unroll
    for (int i = 0; i < 4; i++)
#pragma unroll
      for (int j = 0; j < 4; j++)
        acc[i][j] = __builtin_amdgcn_mfma_f32_16x16x32_bf16(af[i], bfr[j], acc[i][j], 0, 0, 0);
  }

  int grp = lane >> 4, l = lane & 15;
#pragma unroll
  for (int mi = 0; mi < 4; mi++) {
#pragma unroll
    for (int nj = 0; nj < 4; nj++) {
      int col = n0 + wc * 64 + nj * 16 + l;
      float bv = bias ? bias[col] : 0.f;
#pragma unroll
      for (int r = 0; r < 4; r++) {
        int row = m0 + wr * 64 + mi * 16 + grp * 4 + r;
        float v = acc[mi][nj][r] + bv;
        if (OUTMODE == 2) outF[(size_t)row * N + col] += v;
        else outB[(size_t)row * N + col] = f2bf(v);
      }
    }
  }
}

// ----------------------------------------------------------------- 256^2 8-phase GEMM
// OUTMODE 0: bf16 out (+bias). OUTMODE 1: bf16 split-K partial at outB+z*M*N.
// OUTMODE 3: fused swiglu (interleaved gate/up cols; writes bf16 [M][N/2]).
#define BAR __builtin_amdgcn_s_barrier()
#define SCHED0 __builtin_amdgcn_sched_barrier(0)
#define LGKM0 { asm volatile("s_waitcnt lgkmcnt(0)" ::: "memory"); SCHED0; }
#define VMC4 { asm volatile("s_waitcnt vmcnt(4)" ::: "memory"); SCHED0; }
#define VMC0 { asm volatile("s_waitcnt vmcnt(0)" ::: "memory"); SCHED0; }

#define STG_A(p,h,t) { \
  GLD16(pA[h][0] + (size_t)(t)*64, smem + ldsA + (p)*32768 + (h)*16384); \
  GLD16(pA[h][1] + (size_t)(t)*64, smem + ldsA + (p)*32768 + (h)*16384 + 8192); }
#define STG_B(p,h,t) { \
  GLD16(pB[h][0] + (size_t)(t)*64, smem + ldsB + (p)*32768 + (h)*16384); \
  GLD16(pB[h][1] + (size_t)(t)*64, smem + ldsB + (p)*32768 + (h)*16384 + 8192); }

#define DSR_A(p, misel, ks) { \
  _Pragma("unroll") \
  for (int mi = 0; mi < 4; mi++) \
    af[mi] = *(const bf16x8*)(smem + (p)*32768 + aRd + ((misel)*64 + mi*16)*128 + ch[ks]); }
#define DSR_B(p, ks) { \
  _Pragma("unroll") \
  for (int nj = 0; nj < 4; nj++) \
    bfr[ks][nj] = *(const bf16x8*)(smem + (p)*32768 + bRd + nj*2048 + ch[ks]); }

#define MFMA16(misel, ks) { \
  _Pragma("unroll") \
  for (int mi = 0; mi < 4; mi++) \
    _Pragma("unroll") \
    for (int nj = 0; nj < 4; nj++) \
      acc[(misel)*4+mi][nj] = __builtin_amdgcn_mfma_f32_16x16x32_bf16( \
          af[mi], bfr[ks][nj], acc[(misel)*4+mi][nj], 0, 0, 0); }

#define TILE(p, t) { \
  DSR_A(p, 0, 0); DSR_B(p, 0); \
  if ((t)+1 < NT) STG_A(1-(p), 0, (t)+1); \
  SCHED0; BAR; LGKM0; \
  __builtin_amdgcn_s_setprio(1); MFMA16(0, 0); __builtin_amdgcn_s_setprio(0); \
  SCHED0; BAR; \
  DSR_A(p, 0, 1); DSR_B(p, 1); \
  if ((t)+1 < NT) STG_A(1-(p), 1, (t)+1); \
  SCHED0; BAR; LGKM0; \
  __builtin_amdgcn_s_setprio(1); MFMA16(0, 1); __builtin_amdgcn_s_setprio(0); \
  SCHED0; BAR; \
  DSR_A(p, 1, 0); \
  if ((t)+2 < NT) STG_B(p, 0, (t)+2); \
  SCHED0; BAR; LGKM0; \
  __builtin_amdgcn_s_setprio(1); MFMA16(1, 0); __builtin_amdgcn_s_setprio(0); \
  SCHED0; BAR; \
  DSR_A(p, 1, 1); \
  if ((t)+2 < NT) STG_B(p, 1, (t)+2); \
  SCHED0; BAR; LGKM0; \
  __builtin_amdgcn_s_setprio(1); MFMA16(1, 1); __builtin_amdgcn_s_setprio(0); \
  if ((t)+2 < NT) { VMC4; } else { VMC0; } \
  SCHED0; BAR; }

template<int OUTMODE>
__global__ __launch_bounds__(512, 2) void gemm256_kernel(
    const unsigned short* __restrict__ A, const unsigned short* __restrict__ Bt,
    unsigned short* __restrict__ outB, float* __restrict__ outF,
    const float* __restrict__ bias, int M, int N, int Kstride, int Kc)
{
  extern __shared__ char smem[];  // A: [2][256][128B] @0; B: same @65536
  int tid = threadIdx.x;
  int lane = tid & 63, w = tid >> 6;
  int wr = w >> 2, wc = w & 3;
  int l15 = lane & 15, grp = lane >> 4;

  // 2D XCD chunk swizzle: each XCD (bid&7) owns a contiguous (GX/8)-col x GY-row
  // chunk; column-major within the chunk so concurrent blocks share a small
  // B working set in the XCD-private L2. Requires GX%8==0 (all our grids; GY=8).
  int GX = gridDim.x, GY = gridDim.y;
  int bid = blockIdx.y * GX + blockIdx.x;
  int xcd = bid & 7;
  int local = bid >> 3;
  int bx = xcd * (GX >> 3) + local / GY;
  int by = local % GY;
  int m0 = by * 256, n0 = bx * 256;

  int NT = Kc >> 6;
  const unsigned short* Az = A  + (size_t)blockIdx.z * Kc;
  const unsigned short* Bz = Bt + (size_t)blockIdx.z * Kc;

  int srow = lane >> 3;
  int kcol = ((lane & 7) ^ srow) * 8;
  const unsigned short* pA[2][2];
  const unsigned short* pB[2][2];
#pragma unroll
  for (int h = 0; h < 2; h++)
#pragma unroll
    for (int i = 0; i < 2; i++) {
      pA[h][i] = Az + (size_t)(m0 + h*128 + i*64 + w*8 + srow) * Kstride + kcol;
      pB[h][i] = Bz + (size_t)(n0 + h*128 + i*64 + w*8 + srow) * Kstride + kcol;
    }
  int ldsA = w*1024 + lane*16;
  int ldsB = 65536 + w*1024 + lane*16;

  int aRd = (wr*128 + l15) * 128;
  int bRd = 65536 + (wc*64 + l15) * 128;
  int ch[2];
  ch[0] = ((0*4 + grp) ^ (l15 & 7)) * 16;
  ch[1] = ((1*4 + grp) ^ (l15 & 7)) * 16;

  f32x4 z4 = {0.f, 0.f, 0.f, 0.f};
  f32x4 acc[8][4];
#pragma unroll
  for (int i = 0; i < 8; i++)
#pragma unroll
    for (int j = 0; j < 4; j++) acc[i][j] = z4;
  bf16x8 af[4];
  bf16x8 bfr[2][4];

  STG_A(0, 0, 0); STG_A(0, 1, 0); STG_B(0, 0, 0); STG_B(0, 1, 0);
  if (NT > 1) { STG_B(1, 0, 1); STG_B(1, 1, 1); VMC4; } else { VMC0; }
  BAR;

  for (int t = 0; t < NT; t += 2) {   // NT even for all uses (8/24/32)
    TILE(0, t);
    TILE(1, t + 1);
  }

  if (OUTMODE == 3) {
    // interleaved gate/up: nj pairs (0,1)=gate/up of col cbase/2+l15,
    // (2,3)=col cbase/2+16+l15. Output width N/2.
    int cbase = n0 + wc * 64;
    int half = N >> 1;
#pragma unroll
    for (int mi = 0; mi < 8; mi++) {
#pragma unroll
      for (int p = 0; p < 2; p++) {
        int jcol = (cbase >> 1) + p * 16 + l15;
        float bg = bias[jcol];
        float bu = bias[half + jcol];
#pragma unroll
        for (int r = 0; r < 4; r++) {
          int row = m0 + wr * 128 + mi * 16 + grp * 4 + r;
          float g = acc[mi][2 * p][r] + bg;
          float u = acc[mi][2 * p + 1][r] + bu;
          float sv = g / (1.f + __expf(-g)) * u;
          outB[(size_t)row * half + jcol] = f2bf(sv);
        }
      }
    }
  } else {
#pragma unroll
    for (int mi = 0; mi < 8; mi++) {
#pragma unroll
      for (int nj = 0; nj < 4; nj++) {
        int col = n0 + wc * 64 + nj * 16 + l15;
        float bv = (OUTMODE == 0 && bias) ? bias[col] : 0.f;
#pragma unroll
        for (int r = 0; r < 4; r++) {
          int row = m0 + wr * 128 + mi * 16 + grp * 4 + r;
          float v = acc[mi][nj][r] + bv;
          if (OUTMODE == 1)
            outB[(size_t)blockIdx.z * M * N + (size_t)row * N + col] = f2bf(v);
          else
            outB[(size_t)row * N + col] = f2bf(v);
        }
      }
    }
  }
  (void)outF;
}

// ----------------------------------------------------------- attention
// 2 blocks/CU (LDS 79872B). PV in two half-passes (Ps [128][80]).
__global__ __launch_bounds__(256) void attn_kernel(
    const unsigned short* __restrict__ qkv, const int* __restrict__ amask,
    unsigned short* __restrict__ ctx)
{
  __shared__ unsigned short Qs[128 * 80];
  __shared__ unsigned short Ks[128 * 80];
  __shared__ unsigned short Vt[64 * 144];
  __shared__ unsigned short Ps[128 * 80];

  int tid = threadIdx.x, lane = tid & 63, w = tid >> 6;
  int grp = lane >> 4, l = lane & 15;
  int q0 = blockIdx.x * 128;
  int bh = blockIdx.y;
  int b = bh >> 5, h = bh & 31;
  const size_t rs = 3 * DDIM;
  const unsigned short* qbase = qkv + (size_t)(b * SSEQ) * rs + h * HDIM;
  const unsigned short* kbase = qbase + DDIM;
  const unsigned short* vbase = qbase + 2 * DDIM;

#pragma unroll
  for (int i = 0; i < 4; i++) {
    int c = tid + 256 * i;
    int r = c >> 3, part = c & 7;
    us8 v = *(const us8*)(qbase + (size_t)(q0 + r) * rs + part * 8);
    *(us8*)(Qs + r * 80 + part * 8) = v;
  }

  float mrun[2][4], lrun[2][4];
  f32x4 z4 = {0.f, 0.f, 0.f, 0.f};
  f32x4 oacc[2][4];
#pragma unroll
  for (int mi = 0; mi < 2; mi++)
#pragma unroll
    for (int r = 0; r < 4; r++) { mrun[mi][r] = -1e30f; lrun[mi][r] = 0.f; }
#pragma unroll
  for (int mi = 0; mi < 2; mi++)
#pragma unroll
    for (int nj = 0; nj < 4; nj++) oacc[mi][nj] = z4;

  for (int kb = 0; kb < 8; kb++) {
#pragma unroll
    for (int i = 0; i < 4; i++) {
      int c = tid + 256 * i;
      int r = c >> 3, part = c & 7;
      us8 v = *(const us8*)(kbase + (size_t)(kb * 128 + r) * rs + part * 8);
      *(us8*)(Ks + r * 80 + part * 8) = v;
    }
#pragma unroll
    for (int i = 0; i < 2; i++) {
      int bb = tid + 256 * i;
      int hb = bb & 15, sb = bb >> 4;
      int hd0 = hb * 4, s0 = sb * 4;
      us4 rv[4];
#pragma unroll
      for (int j = 0; j < 4; j++)
        rv[j] = *(const us4*)(vbase + (size_t)(kb * 128 + s0 + j) * rs + hd0);
      int s8 = s0 >> 3, rem = s0 & 7;
#pragma unroll
      for (int j2 = 0; j2 < 4; j2++) {
        int hd = hd0 + j2;
        us4 ov;
        ov[0] = rv[0][j2]; ov[1] = rv[1][j2]; ov[2] = rv[2][j2]; ov[3] = rv[3][j2];
        *(us4*)(Vt + hd * 144 + ((s8 ^ (hd >> 2)) * 8) + rem) = ov;
      }
    }
    __syncthreads();

    f32x4 sc[2][8];
#pragma unroll
    for (int mi = 0; mi < 2; mi++)
#pragma unroll
      for (int nj = 0; nj < 8; nj++) sc[mi][nj] = z4;
    __builtin_amdgcn_s_setprio(1);
#pragma unroll
    for (int ks = 0; ks < 2; ks++) {
      bf16x8 aq[2];
#pragma unroll
      for (int mi = 0; mi < 2; mi++)
        aq[mi] = *(const bf16x8*)(Qs + (w * 32 + mi * 16 + l) * 80 + ks * 32 + grp * 8);
#pragma unroll
      for (int nj = 0; nj < 8; nj++) {
        bf16x8 bk = *(const bf16x8*)(Ks + (nj * 16 + l) * 80 + ks * 32 + grp * 8);
#pragma unroll
        for (int mi = 0; mi < 2; mi++)
          sc[mi][nj] = __builtin_amdgcn_mfma_f32_16x16x32_bf16(aq[mi], bk, sc[mi][nj], 0, 0, 0);
      }
    }
    __builtin_amdgcn_s_setprio(0);
    float mb[8];
#pragma unroll
    for (int nj = 0; nj < 8; nj++) {
      int col = kb * 128 + nj * 16 + l;
      mb[nj] = (1.0f - (float)amask[b * SSEQ + col]) * -10000.0f;
    }
#pragma unroll
    for (int mi = 0; mi < 2; mi++)
#pragma unroll
      for (int nj = 0; nj < 8; nj++)
#pragma unroll
        for (int r = 0; r < 4; r++)
          sc[mi][nj][r] = sc[mi][nj][r] * 0.125f + mb[nj];

    float pm[2][4];
#pragma unroll
    for (int mi = 0; mi < 2; mi++)
#pragma unroll
      for (int r = 0; r < 4; r++) {
        float m = sc[mi][0][r];
#pragma unroll
        for (int nj = 1; nj < 8; nj++) m = fmaxf(m, sc[mi][nj][r]);
#pragma unroll
        for (int s = 1; s <= 8; s <<= 1) m = fmaxf(m, __shfl_xor(m, s));
        pm[mi][r] = m;
      }
    float corr[2][4];
#pragma unroll
    for (int mi = 0; mi < 2; mi++)
#pragma unroll
      for (int r = 0; r < 4; r++) {
        float nm = fmaxf(mrun[mi][r], pm[mi][r]);
        corr[mi][r] = __expf(mrun[mi][r] - nm);
        mrun[mi][r] = nm;
      }
    float rsum[2][4];
#pragma unroll
    for (int mi = 0; mi < 2; mi++)
#pragma unroll
      for (int r = 0; r < 4; r++) rsum[mi][r] = 0.f;
#pragma unroll
    for (int mi = 0; mi < 2; mi++)
#pragma unroll
      for (int nj = 0; nj < 8; nj++)
#pragma unroll
        for (int r = 0; r < 4; r++) {
          float p = __expf(sc[mi][nj][r] - mrun[mi][r]);
          sc[mi][nj][r] = p;
          rsum[mi][r] += p;
        }
#pragma unroll
    for (int mi = 0; mi < 2; mi++)
#pragma unroll
      for (int r = 0; r < 4; r++) {
        float s = rsum[mi][r];
#pragma unroll
        for (int m = 1; m <= 8; m <<= 1) s += __shfl_xor(s, m);
        lrun[mi][r] = lrun[mi][r] * corr[mi][r] + s;
      }
#pragma unroll
    for (int mi = 0; mi < 2; mi++)
#pragma unroll
      for (int nj = 0; nj < 4; nj++)
#pragma unroll
        for (int r = 0; r < 4; r++) oacc[mi][nj][r] *= corr[mi][r];

#pragma unroll
    for (int h2 = 0; h2 < 2; h2++) {
#pragma unroll
      for (int mi = 0; mi < 2; mi++)
#pragma unroll
        for (int njl = 0; njl < 4; njl++)
#pragma unroll
          for (int r = 0; r < 4; r++)
            Ps[(w * 32 + mi * 16 + grp * 4 + r) * 80 + njl * 16 + l] =
                f2bf(sc[mi][h2 * 4 + njl][r]);
      __syncthreads();
      __builtin_amdgcn_s_setprio(1);
#pragma unroll
      for (int ksl = 0; ksl < 2; ksl++) {
        bf16x8 pf[2];
#pragma unroll
        for (int mi = 0; mi < 2; mi++)
          pf[mi] = *(const bf16x8*)(Ps + (w * 32 + mi * 16 + l) * 80 + ksl * 32 + grp * 8);
        int s8 = (h2 * 2 + ksl) * 4 + grp;
#pragma unroll
        for (int nj = 0; nj < 4; nj++) {
          int hd = nj * 16 + l;
          bf16x8 vf = *(const bf16x8*)(Vt + hd * 144 + ((s8 ^ (hd >> 2)) * 8));
#pragma unroll
          for (int mi = 0; mi < 2; mi++)
            oacc[mi][nj] = __builtin_amdgcn_mfma_f32_16x16x32_bf16(pf[mi], vf, oacc[mi][nj], 0, 0, 0);
        }
      }
      __builtin_amdgcn_s_setprio(0);
      __syncthreads();
    }
  }

#pragma unroll
  for (int mi = 0; mi < 2; mi++)
#pragma unroll
    for (int nj = 0; nj < 4; nj++)
#pragma unroll
      for (int r = 0; r < 4; r++) {
        int qrow = q0 + w * 32 + mi * 16 + grp * 4 + r;
        int hd = nj * 16 + l;
        float v = oacc[mi][nj][r] / lrun[mi][r];
        ctx[(size_t)(b * SSEQ + qrow) * DDIM + h * HDIM + hd] = f2bf(v);
      }
}

// ----------------------------------------------------------------- swiglu (fallback only)
__global__ __launch_bounds__(256) void swiglu_kernel(
    const unsigned short* __restrict__ gu, unsigned short* __restrict__ a)
{
  size_t idx = ((size_t)blockIdx.x * 256 + threadIdx.x) * 8;
  int r = (int)(idx >> 13);
  int c = (int)(idx & 8191);
  const unsigned short* gp = gu + (size_t)r * (2 * IDIM) + c;
  us8 gv = *(const us8*)gp;
  us8 uv = *(const us8*)(gp + IDIM);
  us8 ov;
#pragma unroll
  for (int j = 0; j < 8; j++) {
    float g = bf2f(gv[j]), u = bf2f(uv[j]);
    ov[j] = f2bf(g / (1.f + __expf(-g)) * u);
  }
  *(us8*)(a + idx) = ov;
}

// ----------------------------------------------------------------- host
extern "C" void kernel_launch(void* const* d_in, const int* in_sizes, int n_in,
                              void* d_out, int out_size, void* d_ws, size_t ws_size,
                              hipStream_t stream) {
  (void)in_sizes; (void)n_in; (void)out_size; (void)ws_size;
  const float* hs    = (const float*)d_in[0];
  const int*   amask = (const int*)d_in[1];
  const float* ln1_g = (const float*)d_in[2];
  const float* ln1_b = (const float*)d_in[3];
  const float* qkv_w = (const float*)d_in[4];
  const float* o_w   = (const float*)d_in[5];
  const float* ln2_g = (const float*)d_in[6];
  const float* ln2_b = (const float*)d_in[7];
  const float* gu_w  = (const float*)d_in[8];
  const float* gu_b  = (const float*)d_in[9];
  const float* down_w = (const float*)d_in[10];
  const float* down_b = (const float*)d_in[11];
  float* out = (float*)d_out;

  char* ws = (char*)d_ws;
  unsigned short* Wt   = (unsigned short*)ws;                    // 64 MiB
  unsigned short* xb   = (unsigned short*)(ws + 67108864);       // 8 MiB
  unsigned short* qkvb = (unsigned short*)(ws + 75497472);       // 24 MiB
  unsigned short* ctxb = (unsigned short*)(ws + 100663296);      // 8 MiB
  unsigned short* gub  = (unsigned short*)(ws + 109051904);      // 64 MiB (fallback gu / split-K partials)
  unsigned short* ab   = qkvb;          // [2048][8192] bf16 = 32 MiB over qkvb+ctxb
  unsigned short* P = gub;              // bf16 split-K partials, 4x8 MiB

  hipError_t e0 = hipFuncSetAttribute(
      reinterpret_cast<const void*>(&gemm256_kernel<0>),
      hipFuncAttributeMaxDynamicSharedMemorySize, 131072);
  hipError_t e1 = hipFuncSetAttribute(
      reinterpret_cast<const void*>(&gemm256_kernel<1>),
      hipFuncAttributeMaxDynamicSharedMemorySize, 131072);
  hipError_t e3 = hipFuncSetAttribute(
      reinterpret_cast<const void*>(&gemm256_kernel<3>),
      hipFuncAttributeMaxDynamicSharedMemorySize, 131072);
  bool use256 = (e0 == hipSuccess && e1 == hipSuccess && e3 == hipSuccess);

  hipMemcpyAsync(out, hs, (size_t)MM * DDIM * sizeof(float),
                 hipMemcpyDeviceToDevice, stream);

  for (int lidx = 0; lidx < LNUM; lidx++) {
    // ---- LN1 (fused with previous layer's down-proj reduce if lidx>0)
    if (use256 && lidx > 0)
      ln_kernel<4><<<MM, 256, 0, stream>>>(out, P, down_b + (lidx - 1) * DDIM,
          ln1_g + lidx * DDIM, ln1_b + lidx * DDIM, xb);
    else
      ln_kernel<0><<<MM, 256, 0, stream>>>(out, nullptr, nullptr,
          ln1_g + lidx * DDIM, ln1_b + lidx * DDIM, xb);

    // ---- QKV
    cvt_t_kernel<0><<<dim3(DDIM / 32, (3 * DDIM) / 32), 256, 0, stream>>>(
        qkv_w + (size_t)lidx * DDIM * 3 * DDIM, Wt, DDIM, 3 * DDIM);
    if (use256)
      gemm256_kernel<0><<<dim3((3 * DDIM) / 256, MM / 256), 512, 131072, stream>>>(
          xb, Wt, qkvb, nullptr, nullptr, MM, 3 * DDIM, DDIM, DDIM);
    else
      gemm_kernel<0><<<dim3((3 * DDIM) / 128, MM / 128), 256, 0, stream>>>(
          xb, Wt, qkvb, nullptr, nullptr, MM, 3 * DDIM, DDIM);

    attn_kernel<<<dim3(SSEQ / 128, BBATCH * HHEADS), 256, 0, stream>>>(qkvb, amask, ctxb);

    // ---- O-proj: split-K=4 into bf16 partials, reduce fused into LN2
    cvt_t_kernel<0><<<dim3(DDIM / 32, DDIM / 32), 256, 0, stream>>>(
        o_w + (size_t)lidx * DDIM * DDIM, Wt, DDIM, DDIM);
    if (use256) {
      gemm256_kernel<1><<<dim3(DDIM / 256, MM / 256, 4), 512, 131072, stream>>>(
          ctxb, Wt, P, nullptr, nullptr, MM, DDIM, DDIM, DDIM / 4);
      ln_kernel<4><<<MM, 256, 0, stream>>>(out, P, nullptr,
          ln2_g + lidx * DDIM, ln2_b + lidx * DDIM, xb);
    } else {
      gemm_kernel<2><<<dim3(DDIM / 128, MM / 128), 256, 0, stream>>>(
          ctxb, Wt, nullptr, out, nullptr, MM, DDIM, DDIM);
      ln_kernel<0><<<MM, 256, 0, stream>>>(out, nullptr, nullptr,
          ln2_g + lidx * DDIM, ln2_b + lidx * DDIM, xb);
    }

    // ---- GU (+fused swiglu when use256): writes ab directly
    if (use256) {
      cvt_t_kernel<1><<<dim3(DDIM / 32, (2 * IDIM) / 32), 256, 0, stream>>>(
          gu_w + (size_t)lidx * DDIM * 2 * IDIM, Wt, DDIM, 2 * IDIM);
      gemm256_kernel<3><<<dim3((2 * IDIM) / 256, MM / 256), 512, 131072, stream>>>(
          xb, Wt, ab, nullptr, gu_b + (size_t)lidx * 2 * IDIM, MM, 2 * IDIM, DDIM, DDIM);
    } else {
      cvt_t_kernel<0><<<dim3(DDIM / 32, (2 * IDIM) / 32), 256, 0, stream>>>(
          gu_w + (size_t)lidx * DDIM * 2 * IDIM, Wt, DDIM, 2 * IDIM);
      gemm_kernel<0><<<dim3((2 * IDIM) / 128, MM / 128), 256, 0, stream>>>(
          xb, Wt, gub, nullptr, gu_b + (size_t)lidx * 2 * IDIM, MM, 2 * IDIM, DDIM);
      swiglu_kernel<<<(MM * IDIM / 8) / 256, 256, 0, stream>>>(gub, ab);
    }

    // ---- Down: split-K=4 into bf16 partials
    cvt_t_kernel<0><<<dim3(IDIM / 32, DDIM / 32), 256, 0, stream>>>(
        down_w + (size_t)lidx * IDIM * DDIM, Wt, IDIM, DDIM);
    if (use256) {
      gemm256_kernel<1><<<dim3(DDIM / 256, MM / 256, 4), 512, 131072, stream>>>(
          ab, Wt, P, nullptr, nullptr, MM, DDIM, IDIM, IDIM / 4);
      if (lidx == LNUM - 1)
        red_kernel<<<(MM * DDIM / 4) / 256, 256, 0, stream>>>(
            out, P, down_b + lidx * DDIM);
      // else: reduce fused into next layer's LN1
    } else {
      gemm_kernel<2><<<dim3(DDIM / 128, MM / 128), 256, 0, stream>>>(
          ab, Wt, nullptr, out, down_b + lidx * DDIM, MM, DDIM, IDIM);
    }
  }
}

// Round 6
// 865.362 us; speedup vs baseline: 1.6360x; 1.0530x over previous
//
#include <hip/hip_runtime.h>

#define LNUM 2
#define BBATCH 2
#define SSEQ 1024
#define DDIM 2048
#define HHEADS 32
#define HDIM 64
#define IDIM 8192
#define MM 2048   // B*S

typedef __attribute__((ext_vector_type(4))) float f32x4;
typedef __attribute__((ext_vector_type(8))) __bf16 bf16x8;
typedef __attribute__((ext_vector_type(4))) unsigned short us4;
typedef __attribute__((ext_vector_type(8))) unsigned short us8;

__device__ __forceinline__ unsigned short f2bf(float f) {
  union { float f; unsigned u; } v; v.f = f;
  unsigned r = v.u + 0x7fffu + ((v.u >> 16) & 1u);
  return (unsigned short)(r >> 16);
}
__device__ __forceinline__ float bf2f(unsigned short b) {
  union { unsigned u; float f; } v; v.u = ((unsigned)b) << 16;
  return v.f;
}

#define GLD16(g, l) __builtin_amdgcn_global_load_lds( \
    (const __attribute__((address_space(1))) void*)(g), \
    (__attribute__((address_space(3))) void*)(l), 16, 0, 0)

// ---------------------------------------------------------------- LayerNorm
// REDSPLIT=0: LN(xin) -> out (bf16). REDSPLIT=4: v = xin + sum of 4 bf16
// partial rows (+rbias); xout = v; LN(v) -> out.
template<int REDSPLIT>
__global__ __launch_bounds__(256) void ln_kernel(
    const float* __restrict__ xin, float* __restrict__ xout,
    const unsigned short* __restrict__ part,
    const float* __restrict__ rbias,
    const float* __restrict__ g, const float* __restrict__ bta,
    unsigned short* __restrict__ out)
{
  int tid = threadIdx.x;
  int lane = tid & 63, w = tid >> 6;
  int row = blockIdx.x;
  const f32x4* xr4 = (const f32x4*)(xin + (size_t)row * DDIM);
  f32x4 v[2];
  float s1 = 0.f, s2 = 0.f;
#pragma unroll
  for (int i = 0; i < 2; i++) {
    int idx4 = tid + 256 * i;
    v[i] = xr4[idx4];
    if (REDSPLIT > 0) {
#pragma unroll
      for (int s = 0; s < REDSPLIT; s++) {
        us4 p = *(const us4*)(part + (size_t)s * MM * DDIM + (size_t)row * DDIM + idx4 * 4);
#pragma unroll
        for (int j = 0; j < 4; j++) v[i][j] += bf2f(p[j]);
      }
      if (rbias) {
        f32x4 bv = *(const f32x4*)(rbias + idx4 * 4);
        v[i] += bv;
      }
      *(f32x4*)(xout + (size_t)row * DDIM + idx4 * 4) = v[i];
    }
#pragma unroll
    for (int j = 0; j < 4; j++) { s1 += v[i][j]; s2 += v[i][j] * v[i][j]; }
  }
#pragma unroll
  for (int m = 1; m < 64; m <<= 1) {
    s1 += __shfl_xor(s1, m);
    s2 += __shfl_xor(s2, m);
  }
  __shared__ float red[8];
  if (lane == 0) { red[w * 2] = s1; red[w * 2 + 1] = s2; }
  __syncthreads();
  s1 = red[0] + red[2] + red[4] + red[6];
  s2 = red[1] + red[3] + red[5] + red[7];
  float mu = s1 / (float)DDIM;
  float var = s2 / (float)DDIM - mu * mu;
  float rstd = rsqrtf(var + 1e-5f);
#pragma unroll
  for (int i = 0; i < 2; i++) {
    int c0 = (tid + 256 * i) * 4;
    us4 o;
#pragma unroll
    for (int j = 0; j < 4; j++)
      o[j] = f2bf((v[i][j] - mu) * rstd * g[c0 + j] + bta[c0 + j]);
    *(us4*)(out + (size_t)row * DDIM + c0) = o;
  }
}

// --------------------------------------------------- final split-K reduce
__global__ __launch_bounds__(256) void red_kernel(
    float* __restrict__ out, const unsigned short* __restrict__ part,
    const float* __restrict__ bias)
{
  size_t i = (size_t)blockIdx.x * 256 + threadIdx.x;   // f32x4 index
  f32x4 o = ((f32x4*)out)[i];
#pragma unroll
  for (int s = 0; s < 4; s++) {
    us4 p = *(const us4*)(part + (size_t)s * MM * DDIM + i * 4);
#pragma unroll
    for (int j = 0; j < 4; j++) o[j] += bf2f(p[j]);
  }
  int col4 = (int)((i * 4) & (DDIM - 1));
  f32x4 bv = *(const f32x4*)(bias + col4);
  o += bv;
  ((f32x4*)out)[i] = o;
}

// ------------------------------------------------- weight convert+transpose
// 4 k-tiles of 32 per block (grid.x = K/128). PERM=0: Wt[n][k] = W[k][n].
// PERM=1 (gate/up interleave): output row p holds orig col
//   perm(p) = (p>>5)*16 + (p&15) + ((p&16) ? N/2 : 0)
template<int PERM>
__global__ __launch_bounds__(256) void cvt_t_kernel(
    const float* __restrict__ W, unsigned short* __restrict__ Wt, int K, int N)
{
  __shared__ float tile[4][32][33];
  int t = threadIdx.x;
  int k0 = blockIdx.x << 7, n0 = blockIdx.y << 5;
  int r = t >> 3, c4 = (t & 7) << 2;
  int colbase;
  if (PERM == 1)
    colbase = (n0 >> 1) + (c4 & 15) + ((c4 & 16) ? (N >> 1) : 0);
  else
    colbase = n0 + c4;
#pragma unroll
  for (int kk = 0; kk < 4; kk++) {
    f32x4 v = *(const f32x4*)(W + (size_t)(k0 + kk * 32 + r) * N + colbase);
    tile[kk][r][c4 + 0] = v[0]; tile[kk][r][c4 + 1] = v[1];
    tile[kk][r][c4 + 2] = v[2]; tile[kk][r][c4 + 3] = v[3];
  }
  __syncthreads();
#pragma unroll
  for (int kk = 0; kk < 4; kk++) {
    us4 o;
#pragma unroll
    for (int j = 0; j < 4; j++) o[j] = f2bf(tile[kk][c4 + j][r]);
    *(us4*)(Wt + (size_t)(n0 + r) * K + k0 + kk * 32 + c4) = o;
  }
}

// ----------------------------------------------------------------- 128^2 GEMM (fallback)
template<int OUTMODE>
__global__ __launch_bounds__(256) void gemm_kernel(
    const unsigned short* __restrict__ A, const unsigned short* __restrict__ Bt,
    unsigned short* __restrict__ outB, float* __restrict__ outF,
    const float* __restrict__ bias, int M, int N, int K)
{
  __shared__ unsigned short As[128 * 32];
  __shared__ unsigned short Bs[128 * 32];
  int tid = threadIdx.x;
  int lane = tid & 63, w = tid >> 6;
  int m0 = blockIdx.y * 128, n0 = blockIdx.x * 128;
  int wr = w >> 1, wc = w & 1;

  f32x4 z4 = {0.f, 0.f, 0.f, 0.f};
  f32x4 acc[4][4];
#pragma unroll
  for (int i = 0; i < 4; i++)
#pragma unroll
    for (int j = 0; j < 4; j++) acc[i][j] = z4;

  int bofs0 = w * 1024 + lane * 16;
  int bofs1 = (4 + w) * 1024 + lane * 16;
  int r0 = bofs0 >> 6, c0 = (bofs0 & 63) >> 1;
  int r1 = bofs1 >> 6, c1 = (bofs1 & 63) >> 1;
  const unsigned short* a0 = A + (size_t)(m0 + r0) * K + c0;
  const unsigned short* a1 = A + (size_t)(m0 + r1) * K + c1;
  const unsigned short* b0 = Bt + (size_t)(n0 + r0) * K + c0;
  const unsigned short* b1 = Bt + (size_t)(n0 + r1) * K + c1;
  unsigned short* lA0 = As + w * 512;
  unsigned short* lA1 = As + (4 + w) * 512;
  unsigned short* lB0 = Bs + w * 512;
  unsigned short* lB1 = Bs + (4 + w) * 512;

  int arow = wr * 64 + (lane & 15);
  int brow = wc * 64 + (lane & 15);
  int koff = (lane >> 4) * 8;

  for (int kt = 0; kt < K; kt += 32) {
    __syncthreads();
    GLD16(a0 + kt, lA0);
    GLD16(a1 + kt, lA1);
    GLD16(b0 + kt, lB0);
    GLD16(b1 + kt, lB1);
    __syncthreads();
    bf16x8 af[4], bfr[4];
#pragma unroll
    for (int i = 0; i < 4; i++)
      af[i] = *(const bf16x8*)(As + (arow + i * 16) * 32 + koff);
#pragma unroll
    for (int j = 0; j < 4; j++)
      bfr[j] = *(const bf16x8*)(Bs + (brow + j * 16) * 32 + koff);
#pragma unroll
    for (int i = 0; i < 4; i++)
#pragma unroll
      for (int j = 0; j < 4; j++)
        acc[i][j] = __builtin_amdgcn_mfma_f32_16x16x32_bf16(af[i], bfr[j], acc[i][j], 0, 0, 0);
  }

  int grp = lane >> 4, l = lane & 15;
#pragma unroll
  for (int mi = 0; mi < 4; mi++) {
#pragma unroll
    for (int nj = 0; nj < 4; nj++) {
      int col = n0 + wc * 64 + nj * 16 + l;
      float bv = bias ? bias[col] : 0.f;
#pragma unroll
      for (int r = 0; r < 4; r++) {
        int row = m0 + wr * 64 + mi * 16 + grp * 4 + r;
        float v = acc[mi][nj][r] + bv;
        if (OUTMODE == 2) outF[(size_t)row * N + col] += v;
        else outB[(size_t)row * N + col] = f2bf(v);
      }
    }
  }
}

// ----------------------------------------------------------------- 256^2 8-phase GEMM
// OUTMODE 0: bf16 out (+bias). OUTMODE 1: bf16 split-K partial at outB+z*M*N.
// OUTMODE 3: fused swiglu (interleaved gate/up cols; writes bf16 [M][N/2]).
#define BAR __builtin_amdgcn_s_barrier()
#define SCHED0 __builtin_amdgcn_sched_barrier(0)
#define LGKM0 { asm volatile("s_waitcnt lgkmcnt(0)" ::: "memory"); SCHED0; }
#define VMC4 { asm volatile("s_waitcnt vmcnt(4)" ::: "memory"); SCHED0; }
#define VMC0 { asm volatile("s_waitcnt vmcnt(0)" ::: "memory"); SCHED0; }

#define STG_A(p,h,t) { \
  GLD16(pA[h][0] + (size_t)(t)*64, smem + ldsA + (p)*32768 + (h)*16384); \
  GLD16(pA[h][1] + (size_t)(t)*64, smem + ldsA + (p)*32768 + (h)*16384 + 8192); }
#define STG_B(p,h,t) { \
  GLD16(pB[h][0] + (size_t)(t)*64, smem + ldsB + (p)*32768 + (h)*16384); \
  GLD16(pB[h][1] + (size_t)(t)*64, smem + ldsB + (p)*32768 + (h)*16384 + 8192); }

#define DSR_A(p, misel, ks) { \
  _Pragma("unroll") \
  for (int mi = 0; mi < 4; mi++) \
    af[mi] = *(const bf16x8*)(smem + (p)*32768 + aRd + ((misel)*64 + mi*16)*128 + ch[ks]); }
#define DSR_B(p, ks) { \
  _Pragma("unroll") \
  for (int nj = 0; nj < 4; nj++) \
    bfr[ks][nj] = *(const bf16x8*)(smem + (p)*32768 + bRd + nj*2048 + ch[ks]); }

#define MFMA16(misel, ks) { \
  _Pragma("unroll") \
  for (int mi = 0; mi < 4; mi++) \
    _Pragma("unroll") \
    for (int nj = 0; nj < 4; nj++) \
      acc[(misel)*4+mi][nj] = __builtin_amdgcn_mfma_f32_16x16x32_bf16( \
          af[mi], bfr[ks][nj], acc[(misel)*4+mi][nj], 0, 0, 0); }

#define TILE(p, t) { \
  DSR_A(p, 0, 0); DSR_B(p, 0); \
  if ((t)+1 < NT) STG_A(1-(p), 0, (t)+1); \
  SCHED0; BAR; LGKM0; \
  __builtin_amdgcn_s_setprio(1); MFMA16(0, 0); __builtin_amdgcn_s_setprio(0); \
  SCHED0; BAR; \
  DSR_A(p, 0, 1); DSR_B(p, 1); \
  if ((t)+1 < NT) STG_A(1-(p), 1, (t)+1); \
  SCHED0; BAR; LGKM0; \
  __builtin_amdgcn_s_setprio(1); MFMA16(0, 1); __builtin_amdgcn_s_setprio(0); \
  SCHED0; BAR; \
  DSR_A(p, 1, 0); \
  if ((t)+2 < NT) STG_B(p, 0, (t)+2); \
  SCHED0; BAR; LGKM0; \
  __builtin_amdgcn_s_setprio(1); MFMA16(1, 0); __builtin_amdgcn_s_setprio(0); \
  SCHED0; BAR; \
  DSR_A(p, 1, 1); \
  if ((t)+2 < NT) STG_B(p, 1, (t)+2); \
  SCHED0; BAR; LGKM0; \
  __builtin_amdgcn_s_setprio(1); MFMA16(1, 1); __builtin_amdgcn_s_setprio(0); \
  if ((t)+2 < NT) { VMC4; } else { VMC0; } \
  SCHED0; BAR; }

template<int OUTMODE>
__global__ __launch_bounds__(512, 2) void gemm256_kernel(
    const unsigned short* __restrict__ A, const unsigned short* __restrict__ Bt,
    unsigned short* __restrict__ outB, float* __restrict__ outF,
    const float* __restrict__ bias, int M, int N, int Kstride, int Kc)
{
  extern __shared__ char smem[];  // A: [2][256][128B] @0; B: same @65536
  int tid = threadIdx.x;
  int lane = tid & 63, w = tid >> 6;
  int wr = w >> 2, wc = w & 3;
  int l15 = lane & 15, grp = lane >> 4;

  // 2D XCD chunk swizzle: each XCD (bid&7) owns a contiguous (GX/8)-col x GY-row
  // chunk; column-major within the chunk. Requires GX%8==0 (all grids; GY=8).
  int GX = gridDim.x, GY = gridDim.y;
  int bid = blockIdx.y * GX + blockIdx.x;
  int xcd = bid & 7;
  int local = bid >> 3;
  int bx = xcd * (GX >> 3) + local / GY;
  int by = local % GY;
  int m0 = by * 256, n0 = bx * 256;

  int NT = Kc >> 6;
  const unsigned short* Az = A  + (size_t)blockIdx.z * Kc;
  const unsigned short* Bz = Bt + (size_t)blockIdx.z * Kc;

  int srow = lane >> 3;
  int kcol = ((lane & 7) ^ srow) * 8;
  const unsigned short* pA[2][2];
  const unsigned short* pB[2][2];
#pragma unroll
  for (int h = 0; h < 2; h++)
#pragma unroll
    for (int i = 0; i < 2; i++) {
      pA[h][i] = Az + (size_t)(m0 + h*128 + i*64 + w*8 + srow) * Kstride + kcol;
      pB[h][i] = Bz + (size_t)(n0 + h*128 + i*64 + w*8 + srow) * Kstride + kcol;
    }
  int ldsA = w*1024 + lane*16;
  int ldsB = 65536 + w*1024 + lane*16;

  int aRd = (wr*128 + l15) * 128;
  int bRd = 65536 + (wc*64 + l15) * 128;
  int ch[2];
  ch[0] = ((0*4 + grp) ^ (l15 & 7)) * 16;
  ch[1] = ((1*4 + grp) ^ (l15 & 7)) * 16;

  f32x4 z4 = {0.f, 0.f, 0.f, 0.f};
  f32x4 acc[8][4];
#pragma unroll
  for (int i = 0; i < 8; i++)
#pragma unroll
    for (int j = 0; j < 4; j++) acc[i][j] = z4;
  bf16x8 af[4];
  bf16x8 bfr[2][4];

  STG_A(0, 0, 0); STG_A(0, 1, 0); STG_B(0, 0, 0); STG_B(0, 1, 0);
  if (NT > 1) { STG_B(1, 0, 1); STG_B(1, 1, 1); VMC4; } else { VMC0; }
  BAR;

  for (int t = 0; t < NT; t += 2) {   // NT even for all uses (8/16/32)
    TILE(0, t);
    TILE(1, t + 1);
  }

  if (OUTMODE == 3) {
    int cbase = n0 + wc * 64;
    int half = N >> 1;
#pragma unroll
    for (int mi = 0; mi < 8; mi++) {
#pragma unroll
      for (int p = 0; p < 2; p++) {
        int jcol = (cbase >> 1) + p * 16 + l15;
        float bg = bias[jcol];
        float bu = bias[half + jcol];
#pragma unroll
        for (int r = 0; r < 4; r++) {
          int row = m0 + wr * 128 + mi * 16 + grp * 4 + r;
          float g = acc[mi][2 * p][r] + bg;
          float u = acc[mi][2 * p + 1][r] + bu;
          float sv = g / (1.f + __expf(-g)) * u;
          outB[(size_t)row * half + jcol] = f2bf(sv);
        }
      }
    }
  } else {
#pragma unroll
    for (int mi = 0; mi < 8; mi++) {
#pragma unroll
      for (int nj = 0; nj < 4; nj++) {
        int col = n0 + wc * 64 + nj * 16 + l15;
        float bv = (OUTMODE == 0 && bias) ? bias[col] : 0.f;
#pragma unroll
        for (int r = 0; r < 4; r++) {
          int row = m0 + wr * 128 + mi * 16 + grp * 4 + r;
          float v = acc[mi][nj][r] + bv;
          if (OUTMODE == 1)
            outB[(size_t)blockIdx.z * M * N + (size_t)row * N + col] = f2bf(v);
          else
            outB[(size_t)row * N + col] = f2bf(v);
        }
      }
    }
  }
  (void)outF;
}

// ----------------------------------------------------------- attention
// 2 blocks/CU (LDS 79872B). PV in two half-passes (Ps [128][80]).
__global__ __launch_bounds__(256) void attn_kernel(
    const unsigned short* __restrict__ qkv, const int* __restrict__ amask,
    unsigned short* __restrict__ ctx)
{
  __shared__ unsigned short Qs[128 * 80];
  __shared__ unsigned short Ks[128 * 80];
  __shared__ unsigned short Vt[64 * 144];
  __shared__ unsigned short Ps[128 * 80];

  int tid = threadIdx.x, lane = tid & 63, w = tid >> 6;
  int grp = lane >> 4, l = lane & 15;
  int q0 = blockIdx.x * 128;
  int bh = blockIdx.y;
  int b = bh >> 5, h = bh & 31;
  const size_t rs = 3 * DDIM;
  const unsigned short* qbase = qkv + (size_t)(b * SSEQ) * rs + h * HDIM;
  const unsigned short* kbase = qbase + DDIM;
  const unsigned short* vbase = qbase + 2 * DDIM;

#pragma unroll
  for (int i = 0; i < 4; i++) {
    int c = tid + 256 * i;
    int r = c >> 3, part = c & 7;
    us8 v = *(const us8*)(qbase + (size_t)(q0 + r) * rs + part * 8);
    *(us8*)(Qs + r * 80 + part * 8) = v;
  }

  float mrun[2][4], lrun[2][4];
  f32x4 z4 = {0.f, 0.f, 0.f, 0.f};
  f32x4 oacc[2][4];
#pragma unroll
  for (int mi = 0; mi < 2; mi++)
#pragma unroll
    for (int r = 0; r < 4; r++) { mrun[mi][r] = -1e30f; lrun[mi][r] = 0.f; }
#pragma unroll
  for (int mi = 0; mi < 2; mi++)
#pragma unroll
    for (int nj = 0; nj < 4; nj++) oacc[mi][nj] = z4;

  for (int kb = 0; kb < 8; kb++) {
#pragma unroll
    for (int i = 0; i < 4; i++) {
      int c = tid + 256 * i;
      int r = c >> 3, part = c & 7;
      us8 v = *(const us8*)(kbase + (size_t)(kb * 128 + r) * rs + part * 8);
      *(us8*)(Ks + r * 80 + part * 8) = v;
    }
#pragma unroll
    for (int i = 0; i < 2; i++) {
      int bb = tid + 256 * i;
      int hb = bb & 15, sb = bb >> 4;
      int hd0 = hb * 4, s0 = sb * 4;
      us4 rv[4];
#pragma unroll
      for (int j = 0; j < 4; j++)
        rv[j] = *(const us4*)(vbase + (size_t)(kb * 128 + s0 + j) * rs + hd0);
      int s8 = s0 >> 3, rem = s0 & 7;
#pragma unroll
      for (int j2 = 0; j2 < 4; j2++) {
        int hd = hd0 + j2;
        us4 ov;
        ov[0] = rv[0][j2]; ov[1] = rv[1][j2]; ov[2] = rv[2][j2]; ov[3] = rv[3][j2];
        *(us4*)(Vt + hd * 144 + ((s8 ^ (hd >> 2)) * 8) + rem) = ov;
      }
    }
    __syncthreads();

    f32x4 sc[2][8];
#pragma unroll
    for (int mi = 0; mi < 2; mi++)
#pragma unroll
      for (int nj = 0; nj < 8; nj++) sc[mi][nj] = z4;
    __builtin_amdgcn_s_setprio(1);
#pragma unroll
    for (int ks = 0; ks < 2; ks++) {
      bf16x8 aq[2];
#pragma unroll
      for (int mi = 0; mi < 2; mi++)
        aq[mi] = *(const bf16x8*)(Qs + (w * 32 + mi * 16 + l) * 80 + ks * 32 + grp * 8);
#pragma unroll
      for (int nj = 0; nj < 8; nj++) {
        bf16x8 bk = *(const bf16x8*)(Ks + (nj * 16 + l) * 80 + ks * 32 + grp * 8);
#pragma unroll
        for (int mi = 0; mi < 2; mi++)
          sc[mi][nj] = __builtin_amdgcn_mfma_f32_16x16x32_bf16(aq[mi], bk, sc[mi][nj], 0, 0, 0);
      }
    }
    __builtin_amdgcn_s_setprio(0);
    float mb[8];
#pragma unroll
    for (int nj = 0; nj < 8; nj++) {
      int col = kb * 128 + nj * 16 + l;
      mb[nj] = (1.0f - (float)amask[b * SSEQ + col]) * -10000.0f;
    }
#pragma unroll
    for (int mi = 0; mi < 2; mi++)
#pragma unroll
      for (int nj = 0; nj < 8; nj++)
#pragma unroll
        for (int r = 0; r < 4; r++)
          sc[mi][nj][r] = sc[mi][nj][r] * 0.125f + mb[nj];

    float pm[2][4];
#pragma unroll
    for (int mi = 0; mi < 2; mi++)
#pragma unroll
      for (int r = 0; r < 4; r++) {
        float m = sc[mi][0][r];
#pragma unroll
        for (int nj = 1; nj < 8; nj++) m = fmaxf(m, sc[mi][nj][r]);
#pragma unroll
        for (int s = 1; s <= 8; s <<= 1) m = fmaxf(m, __shfl_xor(m, s));
        pm[mi][r] = m;
      }
    float corr[2][4];
#pragma unroll
    for (int mi = 0; mi < 2; mi++)
#pragma unroll
      for (int r = 0; r < 4; r++) {
        float nm = fmaxf(mrun[mi][r], pm[mi][r]);
        corr[mi][r] = __expf(mrun[mi][r] - nm);
        mrun[mi][r] = nm;
      }
    float rsum[2][4];
#pragma unroll
    for (int mi = 0; mi < 2; mi++)
#pragma unroll
      for (int r = 0; r < 4; r++) rsum[mi][r] = 0.f;
#pragma unroll
    for (int mi = 0; mi < 2; mi++)
#pragma unroll
      for (int nj = 0; nj < 8; nj++)
#pragma unroll
        for (int r = 0; r < 4; r++) {
          float p = __expf(sc[mi][nj][r] - mrun[mi][r]);
          sc[mi][nj][r] = p;
          rsum[mi][r] += p;
        }
#pragma unroll
    for (int mi = 0; mi < 2; mi++)
#pragma unroll
      for (int r = 0; r < 4; r++) {
        float s = rsum[mi][r];
#pragma unroll
        for (int m = 1; m <= 8; m <<= 1) s += __shfl_xor(s, m);
        lrun[mi][r] = lrun[mi][r] * corr[mi][r] + s;
      }
#pragma unroll
    for (int mi = 0; mi < 2; mi++)
#pragma unroll
      for (int nj = 0; nj < 4; nj++)
#pragma unroll
        for (int r = 0; r < 4; r++) oacc[mi][nj][r] *= corr[mi][r];

#pragma unroll
    for (int h2 = 0; h2 < 2; h2++) {
#pragma unroll
      for (int mi = 0; mi < 2; mi++)
#pragma unroll
        for (int njl = 0; njl < 4; njl++)
#pragma unroll
          for (int r = 0; r < 4; r++)
            Ps[(w * 32 + mi * 16 + grp * 4 + r) * 80 + njl * 16 + l] =
                f2bf(sc[mi][h2 * 4 + njl][r]);
      __syncthreads();
      __builtin_amdgcn_s_setprio(1);
#pragma unroll
      for (int ksl = 0; ksl < 2; ksl++) {
        bf16x8 pf[2];
#pragma unroll
        for (int mi = 0; mi < 2; mi++)
          pf[mi] = *(const bf16x8*)(Ps + (w * 32 + mi * 16 + l) * 80 + ksl * 32 + grp * 8);
        int s8 = (h2 * 2 + ksl) * 4 + grp;
#pragma unroll
        for (int nj = 0; nj < 4; nj++) {
          int hd = nj * 16 + l;
          bf16x8 vf = *(const bf16x8*)(Vt + hd * 144 + ((s8 ^ (hd >> 2)) * 8));
#pragma unroll
          for (int mi = 0; mi < 2; mi++)
            oacc[mi][nj] = __builtin_amdgcn_mfma_f32_16x16x32_bf16(pf[mi], vf, oacc[mi][nj], 0, 0, 0);
        }
      }
      __builtin_amdgcn_s_setprio(0);
      __syncthreads();
    }
  }

#pragma unroll
  for (int mi = 0; mi < 2; mi++)
#pragma unroll
    for (int nj = 0; nj < 4; nj++)
#pragma unroll
      for (int r = 0; r < 4; r++) {
        int qrow = q0 + w * 32 + mi * 16 + grp * 4 + r;
        int hd = nj * 16 + l;
        float v = oacc[mi][nj][r] / lrun[mi][r];
        ctx[(size_t)(b * SSEQ + qrow) * DDIM + h * HDIM + hd] = f2bf(v);
      }
}

// ----------------------------------------------------------------- swiglu (fallback only)
__global__ __launch_bounds__(256) void swiglu_kernel(
    const unsigned short* __restrict__ gu, unsigned short* __restrict__ a)
{
  size_t idx = ((size_t)blockIdx.x * 256 + threadIdx.x) * 8;
  int r = (int)(idx >> 13);
  int c = (int)(idx & 8191);
  const unsigned short* gp = gu + (size_t)r * (2 * IDIM) + c;
  us8 gv = *(const us8*)gp;
  us8 uv = *(const us8*)(gp + IDIM);
  us8 ov;
#pragma unroll
  for (int j = 0; j < 8; j++) {
    float g = bf2f(gv[j]), u = bf2f(uv[j]);
    ov[j] = f2bf(g / (1.f + __expf(-g)) * u);
  }
  *(us8*)(a + idx) = ov;
}

// ----------------------------------------------------------------- host
extern "C" void kernel_launch(void* const* d_in, const int* in_sizes, int n_in,
                              void* d_out, int out_size, void* d_ws, size_t ws_size,
                              hipStream_t stream) {
  (void)in_sizes; (void)n_in; (void)out_size; (void)ws_size;
  const float* hs    = (const float*)d_in[0];
  const int*   amask = (const int*)d_in[1];
  const float* ln1_g = (const float*)d_in[2];
  const float* ln1_b = (const float*)d_in[3];
  const float* qkv_w = (const float*)d_in[4];
  const float* o_w   = (const float*)d_in[5];
  const float* ln2_g = (const float*)d_in[6];
  const float* ln2_b = (const float*)d_in[7];
  const float* gu_w  = (const float*)d_in[8];
  const float* gu_b  = (const float*)d_in[9];
  const float* down_w = (const float*)d_in[10];
  const float* down_b = (const float*)d_in[11];
  float* out = (float*)d_out;

  char* ws = (char*)d_ws;
  unsigned short* Wt   = (unsigned short*)ws;                    // 64 MiB
  unsigned short* xb   = (unsigned short*)(ws + 67108864);       // 8 MiB
  unsigned short* qkvb = (unsigned short*)(ws + 75497472);       // 24 MiB
  unsigned short* ctxb = (unsigned short*)(ws + 100663296);      // 8 MiB
  unsigned short* gub  = (unsigned short*)(ws + 109051904);      // 64 MiB
  unsigned short* ab   = qkvb;          // 32 MiB over qkvb+ctxb (dead then)
  unsigned short* P = gub;              // bf16 split-K partials, 4x8 MiB

  hipError_t e0 = hipFuncSetAttribute(
      reinterpret_cast<const void*>(&gemm256_kernel<0>),
      hipFuncAttributeMaxDynamicSharedMemorySize, 131072);
  hipError_t e1 = hipFuncSetAttribute(
      reinterpret_cast<const void*>(&gemm256_kernel<1>),
      hipFuncAttributeMaxDynamicSharedMemorySize, 131072);
  hipError_t e3 = hipFuncSetAttribute(
      reinterpret_cast<const void*>(&gemm256_kernel<3>),
      hipFuncAttributeMaxDynamicSharedMemorySize, 131072);
  bool use256 = (e0 == hipSuccess && e1 == hipSuccess && e3 == hipSuccess);

  if (!use256) {
    // fallback path keeps the residual stream primed in d_out
    hipMemcpyAsync(out, hs, (size_t)MM * DDIM * sizeof(float),
                   hipMemcpyDeviceToDevice, stream);
  }

  for (int lidx = 0; lidx < LNUM; lidx++) {
    // ---- LN1 (layer 0 reads hs directly; later layers fuse down-proj reduce)
    if (use256 && lidx > 0)
      ln_kernel<4><<<MM, 256, 0, stream>>>(out, out, P, down_b + (lidx - 1) * DDIM,
          ln1_g + lidx * DDIM, ln1_b + lidx * DDIM, xb);
    else
      ln_kernel<0><<<MM, 256, 0, stream>>>(use256 ? hs : out, nullptr, nullptr, nullptr,
          ln1_g + lidx * DDIM, ln1_b + lidx * DDIM, xb);

    // ---- QKV
    cvt_t_kernel<0><<<dim3(DDIM / 128, (3 * DDIM) / 32), 256, 0, stream>>>(
        qkv_w + (size_t)lidx * DDIM * 3 * DDIM, Wt, DDIM, 3 * DDIM);
    if (use256)
      gemm256_kernel<0><<<dim3((3 * DDIM) / 256, MM / 256), 512, 131072, stream>>>(
          xb, Wt, qkvb, nullptr, nullptr, MM, 3 * DDIM, DDIM, DDIM);
    else
      gemm_kernel<0><<<dim3((3 * DDIM) / 128, MM / 128), 256, 0, stream>>>(
          xb, Wt, qkvb, nullptr, nullptr, MM, 3 * DDIM, DDIM);

    attn_kernel<<<dim3(SSEQ / 128, BBATCH * HHEADS), 256, 0, stream>>>(qkvb, amask, ctxb);

    // ---- O-proj: split-K=4 into bf16 partials, reduce fused into LN2
    cvt_t_kernel<0><<<dim3(DDIM / 128, DDIM / 32), 256, 0, stream>>>(
        o_w + (size_t)lidx * DDIM * DDIM, Wt, DDIM, DDIM);
    if (use256) {
      gemm256_kernel<1><<<dim3(DDIM / 256, MM / 256, 4), 512, 131072, stream>>>(
          ctxb, Wt, P, nullptr, nullptr, MM, DDIM, DDIM, DDIM / 4);
      // layer 0: residual source is hs (d_out not yet written); writes h -> out
      ln_kernel<4><<<MM, 256, 0, stream>>>(lidx == 0 ? hs : out, out, P, nullptr,
          ln2_g + lidx * DDIM, ln2_b + lidx * DDIM, xb);
    } else {
      gemm_kernel<2><<<dim3(DDIM / 128, MM / 128), 256, 0, stream>>>(
          ctxb, Wt, nullptr, out, nullptr, MM, DDIM, DDIM);
      ln_kernel<0><<<MM, 256, 0, stream>>>(out, nullptr, nullptr, nullptr,
          ln2_g + lidx * DDIM, ln2_b + lidx * DDIM, xb);
    }

    // ---- GU (+fused swiglu when use256): writes ab directly
    if (use256) {
      cvt_t_kernel<1><<<dim3(DDIM / 128, (2 * IDIM) / 32), 256, 0, stream>>>(
          gu_w + (size_t)lidx * DDIM * 2 * IDIM, Wt, DDIM, 2 * IDIM);
      gemm256_kernel<3><<<dim3((2 * IDIM) / 256, MM / 256), 512, 131072, stream>>>(
          xb, Wt, ab, nullptr, gu_b + (size_t)lidx * 2 * IDIM, MM, 2 * IDIM, DDIM, DDIM);
    } else {
      cvt_t_kernel<0><<<dim3(DDIM / 128, (2 * IDIM) / 32), 256, 0, stream>>>(
          gu_w + (size_t)lidx * DDIM * 2 * IDIM, Wt, DDIM, 2 * IDIM);
      gemm_kernel<0><<<dim3((2 * IDIM) / 128, MM / 128), 256, 0, stream>>>(
          xb, Wt, gub, nullptr, gu_b + (size_t)lidx * 2 * IDIM, MM, 2 * IDIM, DDIM);
      swiglu_kernel<<<(MM * IDIM / 8) / 256, 256, 0, stream>>>(gub, ab);
    }

    // ---- Down: split-K=4 into bf16 partials
    cvt_t_kernel<0><<<dim3(IDIM / 128, DDIM / 32), 256, 0, stream>>>(
        down_w + (size_t)lidx * IDIM * DDIM, Wt, IDIM, DDIM);
    if (use256) {
      gemm256_kernel<1><<<dim3(DDIM / 256, MM / 256, 4), 512, 131072, stream>>>(
          ab, Wt, P, nullptr, nullptr, MM, DDIM, IDIM, IDIM / 4);
      if (lidx == LNUM - 1)
        red_kernel<<<(MM * DDIM / 4) / 256, 256, 0, stream>>>(
            out, P, down_b + lidx * DDIM);
      // else: reduce fused into next layer's LN1
    } else {
      gemm_kernel<2><<<dim3(DDIM / 128, MM / 128), 256, 0, stream>>>(
          ab, Wt, nullptr, out, down_b + lidx * DDIM, MM, DDIM, IDIM);
    }
  }
}